// Round 1
// baseline (1513.814 us; speedup 1.0000x reference)
//
#include <hip/hip_runtime.h>
#include <hip/hip_bf16.h>

// Sizes (fixed by the reference setup)
constexpr int B  = 128;
constexpr int D  = 1024;
constexpr int NV = 36;
constexpr int NL = 20;
constexpr int TSTEPS = 4;
constexpr int BD = B * D;              // 131072
constexpr float EPS = 0.01f;

// Workspace layout (floats)
constexpr long OFF_GATES = 0;              // [B,4096]
constexpr long OFF_LBASE = 524288;         // [B,4096]
constexpr long OFF_HATT  = 1048576;        // [B,D]
constexpr long OFF_CATT  = OFF_HATT + BD;
constexpr long OFF_HLANG = OFF_CATT + BD;
constexpr long OFF_CLANG = OFF_HLANG + BD;
constexpr long OFF_KVS   = OFF_CLANG + BD;
constexpr long OFF_VCTX  = OFF_KVS + BD;
constexpr long OFF_LCTX  = OFF_VCTX + BD;
constexpr long OFF_R     = OFF_LCTX + BD;  // conf relu buffer [B,D]
constexpr long OFF_HL    = OFF_R + BD;     // hL accumulator
constexpr long OFF_CL    = OFF_HL + BD;    // cL accumulator
constexpr long OFF_S     = OFF_CL + BD;    // sum of h_lang over steps (key update)
constexpr long OFF_ACC   = OFF_S + BD;     // accum [B]
constexpr long OFF_SEL   = OFF_ACC + 128;  // sel [B]
constexpr long OFF_COST  = OFF_SEL + 128;  // cost [B]

__device__ __forceinline__ float sigf(float x) { return 1.f / (1.f + expf(-x)); }

// ---------------------------------------------------------------------------
// Init: kvs <- kv_state; zero accumulators; accum=0, sel=1, cost=0
// ---------------------------------------------------------------------------
__global__ __launch_bounds__(256) void init_ws(const float* __restrict__ kv0,
                                               float* __restrict__ ws) {
  int idx = blockIdx.x * 256 + threadIdx.x;
  if (idx < BD) {
    ws[OFF_KVS + idx] = kv0[idx];
    ws[OFF_HL + idx] = 0.f;
    ws[OFF_CL + idx] = 0.f;
    ws[OFF_S + idx]  = 0.f;
  }
  if (idx < B) {
    ws[OFF_ACC + idx]  = 0.f;
    ws[OFF_SEL + idx]  = 1.f;
    ws[OFF_COST + idx] = 0.f;
  }
}

// ---------------------------------------------------------------------------
// Generic fp32 GEMM: C[128,N] = sum_p A_p[128,1024] @ W_p[N,1024]^T
//                    (+ bias0 + bias1 + Cin) (+ relu)
// Tiles: BM=64, BN=64, BK=32; 256 threads (16x16), 4x4 micro-tile.
// LDS stored transposed so fragment reads are float4 (ds_read_b128).
// ---------------------------------------------------------------------------
__global__ __launch_bounds__(256) void gemm_k1024(
    const float* __restrict__ A0, const float* __restrict__ W0, int ws0,
    const float* __restrict__ A1, const float* __restrict__ W1, int ws1,
    const float* __restrict__ A2, const float* __restrict__ W2, int ws2,
    const float* __restrict__ A3, const float* __restrict__ W3, int ws3,
    int P, const float* __restrict__ Cin,
    const float* __restrict__ bias0, const float* __restrict__ bias1,
    float* __restrict__ C, int N, int act) {
  __shared__ __align__(16) float At[32][68];
  __shared__ __align__(16) float Wt[32][68];
  const int tid = threadIdx.x;
  const int tx = tid & 15, ty = tid >> 4;
  const int brow = blockIdx.y * 64, bcol = blockIdx.x * 64;

  float acc[4][4] = {};

  const float* Aarr[4] = {A0, A1, A2, A3};
  const float* Warr[4] = {W0, W1, W2, W3};
  const int wsarr[4] = {ws0, ws1, ws2, ws3};

  for (int p = 0; p < P; ++p) {
    const float* __restrict__ A = Aarr[p];
    const float* __restrict__ W = Warr[p];
    const long wstr = wsarr[p];
    for (int k0 = 0; k0 < 1024; k0 += 32) {
      int idx = tid;
#pragma unroll
      for (int rep = 0; rep < 2; ++rep, idx += 256) {
        const int row = idx >> 3, c4 = (idx & 7) * 4;
        float4 a = *(const float4*)(A + (long)(brow + row) * 1024 + k0 + c4);
        At[c4 + 0][row] = a.x; At[c4 + 1][row] = a.y;
        At[c4 + 2][row] = a.z; At[c4 + 3][row] = a.w;
        float4 w = *(const float4*)(W + (long)(bcol + row) * wstr + k0 + c4);
        Wt[c4 + 0][row] = w.x; Wt[c4 + 1][row] = w.y;
        Wt[c4 + 2][row] = w.z; Wt[c4 + 3][row] = w.w;
      }
      __syncthreads();
#pragma unroll
      for (int kk = 0; kk < 32; ++kk) {
        float4 a = *(const float4*)(&At[kk][ty * 4]);
        float4 b = *(const float4*)(&Wt[kk][tx * 4]);
        float av[4] = {a.x, a.y, a.z, a.w};
        float bv[4] = {b.x, b.y, b.z, b.w};
#pragma unroll
        for (int i2 = 0; i2 < 4; ++i2)
#pragma unroll
          for (int j2 = 0; j2 < 4; ++j2) acc[i2][j2] += av[i2] * bv[j2];
      }
      __syncthreads();
    }
  }

#pragma unroll
  for (int i2 = 0; i2 < 4; ++i2) {
    const int row = brow + ty * 4 + i2;
#pragma unroll
    for (int j2 = 0; j2 < 4; ++j2) {
      const int col = bcol + tx * 4 + j2;
      float v = acc[i2][j2];
      if (bias0) v += bias0[col];
      if (bias1) v += bias1[col];
      const long oidx = (long)row * N + col;
      if (Cin) v += Cin[oidx];
      if (act == 1) v = fmaxf(v, 0.f);
      C[oidx] = v;
    }
  }
}

// ---------------------------------------------------------------------------
// LSTM cell elementwise: gates[B,4096] (i,f,g,o), c_prev -> h, c
// ---------------------------------------------------------------------------
__global__ __launch_bounds__(256) void lstm_cell(const float* __restrict__ gates,
                                                 const float* __restrict__ c_prev,
                                                 float* __restrict__ h,
                                                 float* __restrict__ c) {
  int idx = blockIdx.x * 256 + threadIdx.x;
  if (idx >= BD) return;
  int b = idx >> 10, d = idx & 1023;
  const float* g = gates + (long)b * 4096;
  float gi = g[d], gf = g[1024 + d], gg = g[2048 + d], go = g[3072 + d];
  float cc = sigf(gf) * c_prev[idx] + sigf(gi) * tanhf(gg);
  float hh = sigf(go) * tanhf(cc);
  c[idx] = cc;
  h[idx] = hh;
}

// ---------------------------------------------------------------------------
// Attention step. Softmax over ORIGINAL keys (update is slot-uniform, cancels
// in softmax). Also updates kvs = tanh(kvs + vctx + lctx).
// One block per batch element.
// ---------------------------------------------------------------------------
__global__ __launch_bounds__(256) void attn_step(
    const float* __restrict__ h_att, float* __restrict__ kvs,
    const float* __restrict__ vkey, const float* __restrict__ vval,
    const float* __restrict__ lkey, const float* __restrict__ lval,
    float* __restrict__ vctx, float* __restrict__ lctx) {
  const int b = blockIdx.x, tid = threadIdx.x;
  __shared__ float q[1024];
  __shared__ float wgt[64];
  for (int d = tid; d < 1024; d += 256)
    q[d] = h_att[(long)b * 1024 + d] + kvs[(long)b * 1024 + d];
  __syncthreads();

  const int wave = tid >> 6, lane = tid & 63;
  for (int n = wave; n < NV + NL; n += 4) {
    const float* key = (n < NV) ? (vkey + ((long)b * NV + n) * 1024)
                                : (lkey + ((long)b * NL + (n - NV)) * 1024);
    float s = 0.f;
#pragma unroll
    for (int j = 0; j < 16; ++j) {
      int d = lane + 64 * j;
      s += key[d] * q[d];
    }
    for (int m = 32; m >= 1; m >>= 1) s += __shfl_xor(s, m);
    if (lane == 0) wgt[n] = s * (1.0f / 32.0f);
  }
  __syncthreads();

  if (wave == 0) {
    float x = (lane < NV) ? wgt[lane] : -1e30f;
    float m = x;
    for (int k = 32; k >= 1; k >>= 1) m = fmaxf(m, __shfl_xor(m, k));
    float e = (lane < NV) ? expf(x - m) : 0.f;
    float ssum = e;
    for (int k = 32; k >= 1; k >>= 1) ssum += __shfl_xor(ssum, k);
    if (lane < NV) wgt[lane] = e / ssum;
  } else if (wave == 1) {
    float x = (lane < NL) ? wgt[NV + lane] : -1e30f;
    float m = x;
    for (int k = 32; k >= 1; k >>= 1) m = fmaxf(m, __shfl_xor(m, k));
    float e = (lane < NL) ? expf(x - m) : 0.f;
    float ssum = e;
    for (int k = 32; k >= 1; k >>= 1) ssum += __shfl_xor(ssum, k);
    if (lane < NL) wgt[NV + lane] = e / ssum;
  }
  __syncthreads();

  for (int d = tid; d < 1024; d += 256) {
    float vc = 0.f, lc = 0.f;
#pragma unroll 4
    for (int n = 0; n < NV; ++n) vc += wgt[n] * vval[((long)b * NV + n) * 1024 + d];
#pragma unroll 4
    for (int m2 = 0; m2 < NL; ++m2) lc += wgt[NV + m2] * lval[((long)b * NL + m2) * 1024 + d];
    vctx[(long)b * 1024 + d] = vc;
    lctx[(long)b * 1024 + d] = lc;
    kvs[(long)b * 1024 + d] = tanhf(kvs[(long)b * 1024 + d] + vc + lc);
  }
}

// ---------------------------------------------------------------------------
// Confidence layer 2 + halting update. One block per batch element.
// ---------------------------------------------------------------------------
__global__ __launch_bounds__(256) void conf2_halt(
    const float* __restrict__ r, const float* __restrict__ W2,
    const float* __restrict__ b2, const float* __restrict__ h_lang,
    const float* __restrict__ c_lang, float* __restrict__ ws, float stepnum) {
  const int b = blockIdx.x, tid = threadIdx.x;
  __shared__ float red[256];
  __shared__ float p_sh;
  float part = 0.f;
#pragma unroll
  for (int j = 0; j < 4; ++j) {
    int d = tid + 256 * j;
    part += r[(long)b * 1024 + d] * W2[d];
  }
  red[tid] = part;
  __syncthreads();
  for (int s = 128; s > 0; s >>= 1) {
    if (tid < s) red[tid] += red[tid + s];
    __syncthreads();
  }
  if (tid == 0) p_sh = sigf(red[0] + b2[0]);
  __syncthreads();
  const float p = p_sh;
  const float a_old = ws[OFF_ACC + b];
  const float s_old = ws[OFF_SEL + b];
  const float beta = p * (1.f - a_old);
  const float bs = beta * s_old;
  for (int d = tid; d < 1024; d += 256) {
    const long i = (long)b * 1024 + d;
    float hl = h_lang[i], cl = c_lang[i];
    ws[OFF_HL + i] += bs * hl;
    ws[OFF_CL + i] += bs * cl;
    ws[OFF_S + i] += hl;   // key update is unmasked in the reference
  }
  __syncthreads();
  if (tid == 0) {
    ws[OFF_COST + b] += stepnum * (1.f - p) * s_old;
    const float a_new = a_old + bs;
    ws[OFF_ACC + b] = a_new;
    ws[OFF_SEL + b] = (a_new < 1.f - EPS) ? s_old : 0.f;
  }
}

// ---------------------------------------------------------------------------
// Final output assembly.
// out = [outA(BD), vkey(B*NV*D), lkey(B*NL*D), cost(B), new_h(2BD), new_c(2BD), kvs(BD)]
// ---------------------------------------------------------------------------
constexpr long O1 = BD;                       // end outA
constexpr long O2 = O1 + (long)B * NV * D;    // end vkey
constexpr long O3 = O2 + (long)B * NL * D;    // end lkey
constexpr long O4 = O3 + B;                   // end cost
constexpr long O5 = O4 + 2L * BD;             // end new_h
constexpr long O6 = O5 + 2L * BD;             // end new_c
constexpr long O7 = O6 + BD;                  // end kvs

__global__ __launch_bounds__(256) void finalize(
    const float* __restrict__ ws, const float* __restrict__ vkey0,
    const float* __restrict__ lkey0, const int* __restrict__ it,
    float* __restrict__ out) {
  long idx = (long)blockIdx.x * 256 + threadIdx.x;
  if (idx >= O7) return;
  if (idx < O1) {
    int b = (int)(idx >> 10);
    out[idx] = ws[OFF_HL + idx] / ws[OFF_ACC + b];
  } else if (idx < O2) {
    long r = idx - O1;
    int b = (int)(r / (NV * 1024));
    int d = (int)(r & 1023);
    out[idx] = vkey0[r] + 0.01f * ws[OFF_S + (long)b * 1024 + d];
  } else if (idx < O3) {
    long r = idx - O2;
    int b = (int)(r / (NL * 1024));
    int d = (int)(r & 1023);
    out[idx] = lkey0[r] + 0.01f * ws[OFF_S + (long)b * 1024 + d];
  } else if (idx < O4) {
    int b = (int)(idx - O3);
    out[idx] = ws[OFF_COST + b] * ((it[b] > 0) ? 1.f : 0.f);
  } else if (idx < O5) {
    long r = idx - O4;
    if (r < BD) {
      out[idx] = ws[OFF_HATT + r];               // hA/accum == h_att exactly
    } else {
      long q2 = r - BD;
      int b = (int)(q2 >> 10);
      out[idx] = ws[OFF_HL + q2] / ws[OFF_ACC + b];
    }
  } else if (idx < O6) {
    long r = idx - O5;
    if (r < BD) {
      out[idx] = ws[OFF_CATT + r];               // cA/accum == c_att exactly
    } else {
      long q2 = r - BD;
      int b = (int)(q2 >> 10);
      out[idx] = ws[OFF_CL + q2] / ws[OFF_ACC + b];
    }
  } else {
    out[idx] = ws[OFF_KVS + (idx - O6)];
  }
}

// ---------------------------------------------------------------------------
extern "C" void kernel_launch(void* const* d_in, const int* in_sizes, int n_in,
                              void* d_out, int out_size, void* d_ws, size_t ws_size,
                              hipStream_t stream) {
  const float* xt   = (const float*)d_in[0];
  const int*   it   = (const int*)d_in[1];
  const float* fc   = (const float*)d_in[2];
  const float* vval = (const float*)d_in[3];
  const float* vkey = (const float*)d_in[4];
  const float* lval = (const float*)d_in[5];
  const float* lkey = (const float*)d_in[6];
  const float* kv0  = (const float*)d_in[7];
  const float* sh   = (const float*)d_in[8];   // [2,B,D]
  const float* sc   = (const float*)d_in[9];   // [2,B,D]
  // d_in[10] = max_att_step (always 4 in this harness)
  const float* aWih = (const float*)d_in[11];  // [4096,3072]
  const float* aWhh = (const float*)d_in[12];  // [4096,1024]
  const float* abih = (const float*)d_in[13];
  const float* abhh = (const float*)d_in[14];
  const float* lWih = (const float*)d_in[15];  // [4096,3072]
  const float* lWhh = (const float*)d_in[16];  // [4096,1024]
  const float* lbih = (const float*)d_in[17];
  const float* lbhh = (const float*)d_in[18];
  const float* cW1  = (const float*)d_in[19];  // [1024,1024]
  const float* cb1  = (const float*)d_in[20];
  const float* cW2  = (const float*)d_in[21];  // [1,1024]
  const float* cb2  = (const float*)d_in[22];

  float* ws = (float*)d_ws;
  float* gates  = ws + OFF_GATES;
  float* lbase  = ws + OFF_LBASE;
  float* h_att  = ws + OFF_HATT;
  float* c_att  = ws + OFF_CATT;
  float* h_lang = ws + OFF_HLANG;
  float* c_lang = ws + OFF_CLANG;
  float* kvs    = ws + OFF_KVS;
  float* vctx   = ws + OFF_VCTX;
  float* lctx   = ws + OFF_LCTX;
  float* rbuf   = ws + OFF_R;

  const float* sh1 = sh + BD;  // state_h[1]
  const float* sc0 = sc;       // state_c[0]
  const float* sc1 = sc + BD;  // state_c[1]

  init_ws<<<512, 256, 0, stream>>>(kv0, ws);

  // att gates: concat(state_h1, fc, xt) @ att_Wih^T + state_h0 @ att_Whh^T + biases
  gemm_k1024<<<dim3(64, 2), 256, 0, stream>>>(
      sh1, aWih + 0, 3072, fc, aWih + 1024, 3072, xt, aWih + 2048, 3072,
      sh, aWhh, 1024, 4, nullptr, abih, abhh, gates, 4096, 0);
  lstm_cell<<<512, 256, 0, stream>>>(gates, sc0, h_att, c_att);

  // lang base (loop-invariant): state_h1 @ lang_Whh^T + h_att @ lang_Wih[:,2D:3D]^T + biases
  gemm_k1024<<<dim3(64, 2), 256, 0, stream>>>(
      sh1, lWhh, 1024, h_att, lWih + 2048, 3072, nullptr, nullptr, 0,
      nullptr, nullptr, 0, 2, nullptr, lbih, lbhh, lbase, 4096, 0);

  for (int i = 0; i < TSTEPS; ++i) {
    attn_step<<<128, 256, 0, stream>>>(h_att, kvs, vkey, vval, lkey, lval, vctx, lctx);
    gemm_k1024<<<dim3(64, 2), 256, 0, stream>>>(
        vctx, lWih + 0, 3072, lctx, lWih + 1024, 3072, nullptr, nullptr, 0,
        nullptr, nullptr, 0, 2, lbase, nullptr, nullptr, gates, 4096, 0);
    lstm_cell<<<512, 256, 0, stream>>>(gates, sc1, h_lang, c_lang);
    gemm_k1024<<<dim3(16, 2), 256, 0, stream>>>(
        h_lang, cW1, 1024, nullptr, nullptr, 0, nullptr, nullptr, 0,
        nullptr, nullptr, 0, 1, nullptr, cb1, nullptr, rbuf, 1024, 1);
    conf2_halt<<<128, 256, 0, stream>>>(rbuf, cW2, cb2, h_lang, c_lang, ws,
                                        (float)(i + 1));
  }

  finalize<<<(int)((O7 + 255) / 256), 256, 0, stream>>>(ws, vkey, lkey, it,
                                                        (float*)d_out);
}

// Round 2
// 290.225 us; speedup vs baseline: 5.2160x; 5.2160x over previous
//
#include <hip/hip_runtime.h>
#include <hip/hip_bf16.h>

// Sizes (fixed by the reference setup)
constexpr int B  = 128;
constexpr int D  = 1024;
constexpr int NV = 36;
constexpr int NL = 20;
constexpr int TSTEPS = 4;
constexpr int BD = B * D;              // 131072
constexpr float EPS = 0.01f;

// Workspace layout (floats)
constexpr long GP_STRIDE = 524288;         // one partial slot: [128][4096] f32
constexpr long OFF_GP    = 0;              // 4 slots
constexpr long OFF_LBASE = 4 * GP_STRIDE;  // [B,4096]
constexpr long OFF_HATT  = OFF_LBASE + 524288;
constexpr long OFF_CATT  = OFF_HATT + BD;
constexpr long OFF_HLANG = OFF_CATT + BD;
constexpr long OFF_CLANG = OFF_HLANG + BD;
constexpr long OFF_KVS   = OFF_CLANG + BD;
constexpr long OFF_VCTX  = OFF_KVS + BD;
constexpr long OFF_LCTX  = OFF_VCTX + BD;
constexpr long OFF_WGT   = OFF_LCTX + BD;   // [128][64] softmax weights
constexpr long OFF_HL    = OFF_WGT + 8192;  // hL accumulator
constexpr long OFF_CL    = OFF_HL + BD;
constexpr long OFF_S     = OFF_CL + BD;     // sum of h_lang over steps
constexpr long OFF_ACC   = OFF_S + BD;
constexpr long OFF_SEL   = OFF_ACC + 128;
constexpr long OFF_COST  = OFF_SEL + 128;

typedef float f32x4 __attribute__((ext_vector_type(4)));
typedef short s16x8 __attribute__((ext_vector_type(8)));

__device__ __forceinline__ float sigf(float x) { return 1.f / (1.f + expf(-x)); }

__device__ __forceinline__ short f2bf(float f) {
  __hip_bfloat16 h = __float2bfloat16(f);
  return *reinterpret_cast<short*>(&h);
}

// ---------------------------------------------------------------------------
// Init: kvs <- kv_state; zero accumulators; accum=0, sel=1, cost=0
// ---------------------------------------------------------------------------
__global__ __launch_bounds__(256) void init_ws(const float* __restrict__ kv0,
                                               float* __restrict__ ws) {
  int idx = blockIdx.x * 256 + threadIdx.x;
  if (idx < BD) {
    ws[OFF_KVS + idx] = kv0[idx];
    ws[OFF_HL + idx] = 0.f;
    ws[OFF_CL + idx] = 0.f;
    ws[OFF_S + idx]  = 0.f;
  }
  if (idx < B) {
    ws[OFF_ACC + idx]  = 0.f;
    ws[OFF_SEL + idx]  = 1.f;
    ws[OFF_COST + idx] = 0.f;
  }
}

// ---------------------------------------------------------------------------
// MFMA bf16 GEMM with fp32-in-flight conversion and K-split partials.
// Computes partial[g*KS+z][128][N] = A_g[128, z*klen : (z+1)*klen] @ W_g^T
// grid = (N/64, nchunks, KS); block = 256 (4 waves).
// Tile: BM=128 (full M), BN=64, BK=64. Each wave: 64x32 out = 4x2 frags.
// LDS padded to 72 shorts/row -> 2-way max bank aliasing (free).
// ---------------------------------------------------------------------------
struct GemmArgs {
  const float* A[4];   // each [128,1024] chunk, row stride 1024
  const float* W[4];   // each [N, wstride] row-major, cols [0,1024) used
  int wstride[4];
};

__global__ __launch_bounds__(256) void gemm_mfma(GemmArgs ga, int N, int KS,
                                                 float* __restrict__ gpart) {
  const int g = blockIdx.y, z = blockIdx.z;
  const float* __restrict__ A = ga.A[g];
  const float* __restrict__ W = ga.W[g];
  const long wstr = ga.wstride[g];
  const int klen = 1024 / KS;
  const int koff = z * klen;
  const int bcol = blockIdx.x * 64;
  float* __restrict__ out = gpart + (long)(g * KS + z) * GP_STRIDE;

  __shared__ __align__(16) short As[128][72];
  __shared__ __align__(16) short Ws[64][72];

  const int tid = threadIdx.x;
  const int wave = tid >> 6, lane = tid & 63;
  const int wr = wave >> 1, wc = wave & 1;
  const int lrow = lane & 15;          // fragment row/col within 16
  const int lk8  = (lane >> 4) * 8;    // k-subchunk base (0,8,16,24)

  f32x4 acc[4][2];
#pragma unroll
  for (int m = 0; m < 4; ++m)
#pragma unroll
    for (int n = 0; n < 2; ++n) acc[m][n] = (f32x4){0.f, 0.f, 0.f, 0.f};

  for (int kt = 0; kt < klen; kt += 64) {
    const int kbase = koff + kt;
    // stage A: 128 rows x 64 cols -> 2048 float4 loads, 8 per thread
#pragma unroll
    for (int i = 0; i < 8; ++i) {
      int idx = tid + i * 256;
      int r = idx >> 4, c4 = (idx & 15) * 4;
      float4 v = *(const float4*)(A + (long)r * 1024 + kbase + c4);
      short4 s = {f2bf(v.x), f2bf(v.y), f2bf(v.z), f2bf(v.w)};
      *(short4*)(&As[r][c4]) = s;
    }
    // stage W: 64 rows x 64 cols -> 1024 float4 loads, 4 per thread
#pragma unroll
    for (int i = 0; i < 4; ++i) {
      int idx = tid + i * 256;
      int r = idx >> 4, c4 = (idx & 15) * 4;
      float4 v = *(const float4*)(W + (long)(bcol + r) * wstr + kbase + c4);
      short4 s = {f2bf(v.x), f2bf(v.y), f2bf(v.z), f2bf(v.w)};
      *(short4*)(&Ws[r][c4]) = s;
    }
    __syncthreads();
#pragma unroll
    for (int kk = 0; kk < 64; kk += 32) {
      s16x8 af[4], bf[2];
#pragma unroll
      for (int m = 0; m < 4; ++m)
        af[m] = *(const s16x8*)(&As[wr * 64 + m * 16 + lrow][kk + lk8]);
#pragma unroll
      for (int n = 0; n < 2; ++n)
        bf[n] = *(const s16x8*)(&Ws[wc * 32 + n * 16 + lrow][kk + lk8]);
#pragma unroll
      for (int m = 0; m < 4; ++m)
#pragma unroll
        for (int n = 0; n < 2; ++n)
          acc[m][n] = __builtin_amdgcn_mfma_f32_16x16x32_bf16(
              af[m], bf[n], acc[m][n], 0, 0, 0);
    }
    __syncthreads();
  }

  // write fp32 partial: C/D layout col=lane&15, row=(lane>>4)*4+reg
#pragma unroll
  for (int m = 0; m < 4; ++m) {
#pragma unroll
    for (int n = 0; n < 2; ++n) {
      const int col = bcol + wc * 32 + n * 16 + lrow;
#pragma unroll
      for (int r = 0; r < 4; ++r) {
        const int row = wr * 64 + m * 16 + (lane >> 4) * 4 + r;
        out[(long)row * N + col] = acc[m][n][r];
      }
    }
  }
}

// ---------------------------------------------------------------------------
// LSTM cell: gates = sum of 4 partials (+extra) (+bih+bhh); i,f,g,o -> h,c
// ---------------------------------------------------------------------------
__global__ __launch_bounds__(256) void lstm_cell(
    const float* __restrict__ gp, const float* __restrict__ extra,
    const float* __restrict__ bih, const float* __restrict__ bhh,
    const float* __restrict__ c_prev, float* __restrict__ h,
    float* __restrict__ c) {
  int idx = blockIdx.x * 256 + threadIdx.x;
  if (idx >= BD) return;
  int b = idx >> 10, d = idx & 1023;
  const long base = (long)b * 4096 + d;
  float gv[4];
#pragma unroll
  for (int gi = 0; gi < 4; ++gi) {
    const long o = base + gi * 1024;
    float v = gp[o] + gp[GP_STRIDE + o] + gp[2 * GP_STRIDE + o] + gp[3 * GP_STRIDE + o];
    if (extra) v += extra[o];
    if (bih) v += bih[gi * 1024 + d] + bhh[gi * 1024 + d];
    gv[gi] = v;
  }
  float cc = sigf(gv[1]) * c_prev[idx] + sigf(gv[0]) * tanhf(gv[2]);
  float hh = sigf(gv[3]) * tanhf(cc);
  c[idx] = cc;
  h[idx] = hh;
}

// ---------------------------------------------------------------------------
// reduce4: out = p0+p1+p2+p3 + bih + bhh   (for lbase)
// ---------------------------------------------------------------------------
__global__ __launch_bounds__(256) void reduce4(
    const float* __restrict__ gp, const float* __restrict__ bih,
    const float* __restrict__ bhh, float* __restrict__ out) {
  long idx = (long)blockIdx.x * 256 + threadIdx.x;
  if (idx >= (long)B * 4096) return;
  int col = (int)(idx & 4095);
  out[idx] = gp[idx] + gp[GP_STRIDE + idx] + gp[2 * GP_STRIDE + idx] +
             gp[3 * GP_STRIDE + idx] + bih[col] + bhh[col];
}

// ---------------------------------------------------------------------------
// Attention logits: q = h_att + kvs; softmax over original keys (the in-loop
// key update is slot-uniform so it cancels in softmax). One block per b.
// ---------------------------------------------------------------------------
__global__ __launch_bounds__(256) void attn_logits(
    const float* __restrict__ h_att, const float* __restrict__ kvs,
    const float* __restrict__ vkey, const float* __restrict__ lkey,
    float* __restrict__ wgt_out) {
  const int b = blockIdx.x, tid = threadIdx.x;
  __shared__ float q[1024];
  __shared__ float wgt[64];
  for (int d = tid; d < 1024; d += 256)
    q[d] = h_att[(long)b * 1024 + d] + kvs[(long)b * 1024 + d];
  __syncthreads();

  const int wave = tid >> 6, lane = tid & 63;
  for (int n = wave; n < NV + NL; n += 4) {
    const float* key = (n < NV) ? (vkey + ((long)b * NV + n) * 1024)
                                : (lkey + ((long)b * NL + (n - NV)) * 1024);
    float s = 0.f;
#pragma unroll
    for (int j = 0; j < 16; ++j) {
      int d = lane + 64 * j;
      s += key[d] * q[d];
    }
    for (int m = 32; m >= 1; m >>= 1) s += __shfl_xor(s, m);
    if (lane == 0) wgt[n] = s * (1.0f / 32.0f);
  }
  __syncthreads();

  if (wave == 0) {
    float x = (lane < NV) ? wgt[lane] : -1e30f;
    float m = x;
    for (int k = 32; k >= 1; k >>= 1) m = fmaxf(m, __shfl_xor(m, k));
    float e = (lane < NV) ? expf(x - m) : 0.f;
    float ssum = e;
    for (int k = 32; k >= 1; k >>= 1) ssum += __shfl_xor(ssum, k);
    if (lane < NV) wgt_out[b * 64 + lane] = e / ssum;
  } else if (wave == 1) {
    float x = (lane < NL) ? wgt[NV + lane] : -1e30f;
    float m = x;
    for (int k = 32; k >= 1; k >>= 1) m = fmaxf(m, __shfl_xor(m, k));
    float e = (lane < NL) ? expf(x - m) : 0.f;
    float ssum = e;
    for (int k = 32; k >= 1; k >>= 1) ssum += __shfl_xor(ssum, k);
    if (lane < NL) wgt_out[b * 64 + NV + lane] = e / ssum;
  }
}

// ---------------------------------------------------------------------------
// Attention context + kvs update. grid (128, 2): block handles 512 d-cols.
// ---------------------------------------------------------------------------
__global__ __launch_bounds__(256) void attn_ctx(
    const float* __restrict__ wgt, const float* __restrict__ vval,
    const float* __restrict__ lval, float* __restrict__ kvs,
    float* __restrict__ vctx, float* __restrict__ lctx) {
  const int b = blockIdx.x, half = blockIdx.y, tid = threadIdx.x;
  __shared__ float w[64];
  if (tid < NV + NL) w[tid] = wgt[b * 64 + tid];
  __syncthreads();
  const int d = half * 512 + tid * 2;
  float vcx = 0.f, vcy = 0.f, lcx = 0.f, lcy = 0.f;
  const float* vp = vval + (long)b * NV * 1024 + d;
#pragma unroll 4
  for (int n = 0; n < NV; ++n) {
    float2 v = *(const float2*)(vp + (long)n * 1024);
    vcx += w[n] * v.x;
    vcy += w[n] * v.y;
  }
  const float* lp = lval + (long)b * NL * 1024 + d;
#pragma unroll 4
  for (int n = 0; n < NL; ++n) {
    float2 v = *(const float2*)(lp + (long)n * 1024);
    lcx += w[NV + n] * v.x;
    lcy += w[NV + n] * v.y;
  }
  const long i = (long)b * 1024 + d;
  vctx[i] = vcx; vctx[i + 1] = vcy;
  lctx[i] = lcx; lctx[i + 1] = lcy;
  kvs[i]     = tanhf(kvs[i] + vcx + lcx);
  kvs[i + 1] = tanhf(kvs[i + 1] + vcy + lcy);
}

// ---------------------------------------------------------------------------
// Confidence (partials -> relu -> dot W2 -> sigmoid) + halting update.
// Conf partials live in gp slots 0..3 with layout [128][1024].
// ---------------------------------------------------------------------------
__global__ __launch_bounds__(256) void conf2_halt(
    const float* __restrict__ gp, const float* __restrict__ cb1,
    const float* __restrict__ W2, const float* __restrict__ b2,
    const float* __restrict__ h_lang, const float* __restrict__ c_lang,
    float* __restrict__ ws, float stepnum) {
  const int b = blockIdx.x, tid = threadIdx.x;
  __shared__ float red[256];
  __shared__ float p_sh;
  float part = 0.f;
#pragma unroll
  for (int j = 0; j < 4; ++j) {
    int d = tid + 256 * j;
    const long o = (long)b * 1024 + d;
    float rv = gp[o] + gp[GP_STRIDE + o] + gp[2 * GP_STRIDE + o] +
               gp[3 * GP_STRIDE + o] + cb1[d];
    rv = fmaxf(rv, 0.f);
    part += rv * W2[d];
  }
  red[tid] = part;
  __syncthreads();
  for (int s = 128; s > 0; s >>= 1) {
    if (tid < s) red[tid] += red[tid + s];
    __syncthreads();
  }
  if (tid == 0) p_sh = sigf(red[0] + b2[0]);
  __syncthreads();
  const float p = p_sh;
  const float a_old = ws[OFF_ACC + b];
  const float s_old = ws[OFF_SEL + b];
  const float beta = p * (1.f - a_old);
  const float bs = beta * s_old;
  for (int d = tid; d < 1024; d += 256) {
    const long i = (long)b * 1024 + d;
    float hl = h_lang[i], cl = c_lang[i];
    ws[OFF_HL + i] += bs * hl;
    ws[OFF_CL + i] += bs * cl;
    ws[OFF_S + i] += hl;   // key update is unmasked in the reference
  }
  __syncthreads();
  if (tid == 0) {
    ws[OFF_COST + b] += stepnum * (1.f - p) * s_old;
    const float a_new = a_old + bs;
    ws[OFF_ACC + b] = a_new;
    ws[OFF_SEL + b] = (a_new < 1.f - EPS) ? s_old : 0.f;
  }
}

// ---------------------------------------------------------------------------
// Final output assembly.
// out = [outA(BD), vkey, lkey, cost(B), new_h(2BD), new_c(2BD), kvs(BD)]
// ---------------------------------------------------------------------------
constexpr long O1 = BD;
constexpr long O2 = O1 + (long)B * NV * D;
constexpr long O3 = O2 + (long)B * NL * D;
constexpr long O4 = O3 + B;
constexpr long O5 = O4 + 2L * BD;
constexpr long O6 = O5 + 2L * BD;
constexpr long O7 = O6 + BD;

__global__ __launch_bounds__(256) void finalize(
    const float* __restrict__ ws, const float* __restrict__ vkey0,
    const float* __restrict__ lkey0, const int* __restrict__ it,
    float* __restrict__ out) {
  long idx = (long)blockIdx.x * 256 + threadIdx.x;
  if (idx >= O7) return;
  if (idx < O1) {
    int b = (int)(idx >> 10);
    out[idx] = ws[OFF_HL + idx] / ws[OFF_ACC + b];
  } else if (idx < O2) {
    long r = idx - O1;
    int b = (int)(r / (NV * 1024));
    int d = (int)(r & 1023);
    out[idx] = vkey0[r] + 0.01f * ws[OFF_S + (long)b * 1024 + d];
  } else if (idx < O3) {
    long r = idx - O2;
    int b = (int)(r / (NL * 1024));
    int d = (int)(r & 1023);
    out[idx] = lkey0[r] + 0.01f * ws[OFF_S + (long)b * 1024 + d];
  } else if (idx < O4) {
    int b = (int)(idx - O3);
    out[idx] = ws[OFF_COST + b] * ((it[b] > 0) ? 1.f : 0.f);
  } else if (idx < O5) {
    long r = idx - O4;
    if (r < BD) {
      out[idx] = ws[OFF_HATT + r];    // hA/accum == h_att exactly
    } else {
      long q2 = r - BD;
      int b = (int)(q2 >> 10);
      out[idx] = ws[OFF_HL + q2] / ws[OFF_ACC + b];
    }
  } else if (idx < O6) {
    long r = idx - O5;
    if (r < BD) {
      out[idx] = ws[OFF_CATT + r];    // cA/accum == c_att exactly
    } else {
      long q2 = r - BD;
      int b = (int)(q2 >> 10);
      out[idx] = ws[OFF_CL + q2] / ws[OFF_ACC + b];
    }
  } else {
    out[idx] = ws[OFF_KVS + (idx - O6)];
  }
}

// ---------------------------------------------------------------------------
extern "C" void kernel_launch(void* const* d_in, const int* in_sizes, int n_in,
                              void* d_out, int out_size, void* d_ws, size_t ws_size,
                              hipStream_t stream) {
  const float* xt   = (const float*)d_in[0];
  const int*   it   = (const int*)d_in[1];
  const float* fc   = (const float*)d_in[2];
  const float* vval = (const float*)d_in[3];
  const float* vkey = (const float*)d_in[4];
  const float* lval = (const float*)d_in[5];
  const float* lkey = (const float*)d_in[6];
  const float* kv0  = (const float*)d_in[7];
  const float* sh   = (const float*)d_in[8];   // [2,B,D]
  const float* sc   = (const float*)d_in[9];   // [2,B,D]
  // d_in[10] = max_att_step (4)
  const float* aWih = (const float*)d_in[11];  // [4096,3072]
  const float* aWhh = (const float*)d_in[12];  // [4096,1024]
  const float* abih = (const float*)d_in[13];
  const float* abhh = (const float*)d_in[14];
  const float* lWih = (const float*)d_in[15];  // [4096,3072]
  const float* lWhh = (const float*)d_in[16];  // [4096,1024]
  const float* lbih = (const float*)d_in[17];
  const float* lbhh = (const float*)d_in[18];
  const float* cW1  = (const float*)d_in[19];  // [1024,1024]
  const float* cb1  = (const float*)d_in[20];
  const float* cW2  = (const float*)d_in[21];  // [1,1024]
  const float* cb2  = (const float*)d_in[22];

  float* ws = (float*)d_ws;
  float* gp     = ws + OFF_GP;
  float* lbase  = ws + OFF_LBASE;
  float* h_att  = ws + OFF_HATT;
  float* c_att  = ws + OFF_CATT;
  float* h_lang = ws + OFF_HLANG;
  float* c_lang = ws + OFF_CLANG;
  float* kvs    = ws + OFF_KVS;
  float* vctx   = ws + OFF_VCTX;
  float* lctx   = ws + OFF_LCTX;
  float* wgt    = ws + OFF_WGT;

  const float* sh1 = sh + BD;  // state_h[1]
  const float* sc0 = sc;       // state_c[0]
  const float* sc1 = sc + BD;  // state_c[1]

  init_ws<<<512, 256, 0, stream>>>(kv0, ws);

  // att gates: [sh1,fc,xt]@aWih^T + sh0@aWhh^T  (4 K-chunks, KS=1 -> 256 blocks)
  {
    GemmArgs ga;
    ga.A[0] = sh1; ga.W[0] = aWih;        ga.wstride[0] = 3072;
    ga.A[1] = fc;  ga.W[1] = aWih + 1024; ga.wstride[1] = 3072;
    ga.A[2] = xt;  ga.W[2] = aWih + 2048; ga.wstride[2] = 3072;
    ga.A[3] = sh;  ga.W[3] = aWhh;        ga.wstride[3] = 1024;
    gemm_mfma<<<dim3(64, 4, 1), 256, 0, stream>>>(ga, 4096, 1, gp);
  }
  lstm_cell<<<512, 256, 0, stream>>>(gp, nullptr, abih, abhh, sc0, h_att, c_att);

  // lbase (loop-invariant): sh1@lWhh^T + h_att@lWih[:,2048:]^T + biases
  {
    GemmArgs ga;
    ga.A[0] = sh1;   ga.W[0] = lWhh;        ga.wstride[0] = 1024;
    ga.A[1] = h_att; ga.W[1] = lWih + 2048; ga.wstride[1] = 3072;
    ga.A[2] = nullptr; ga.W[2] = nullptr; ga.wstride[2] = 0;
    ga.A[3] = nullptr; ga.W[3] = nullptr; ga.wstride[3] = 0;
    gemm_mfma<<<dim3(64, 2, 2), 256, 0, stream>>>(ga, 4096, 2, gp);
  }
  reduce4<<<2048, 256, 0, stream>>>(gp, lbih, lbhh, lbase);

  for (int i = 0; i < TSTEPS; ++i) {
    attn_logits<<<128, 256, 0, stream>>>(h_att, kvs, vkey, lkey, wgt);
    attn_ctx<<<dim3(128, 2), 256, 0, stream>>>(wgt, vval, lval, kvs, vctx, lctx);
    {
      GemmArgs ga;
      ga.A[0] = vctx; ga.W[0] = lWih;        ga.wstride[0] = 3072;
      ga.A[1] = lctx; ga.W[1] = lWih + 1024; ga.wstride[1] = 3072;
      ga.A[2] = nullptr; ga.W[2] = nullptr; ga.wstride[2] = 0;
      ga.A[3] = nullptr; ga.W[3] = nullptr; ga.wstride[3] = 0;
      gemm_mfma<<<dim3(64, 2, 2), 256, 0, stream>>>(ga, 4096, 2, gp);
    }
    lstm_cell<<<512, 256, 0, stream>>>(gp, lbase, nullptr, nullptr, sc1,
                                       h_lang, c_lang);
    {
      GemmArgs ga;
      ga.A[0] = h_lang; ga.W[0] = cW1; ga.wstride[0] = 1024;
      ga.A[1] = nullptr; ga.W[1] = nullptr; ga.wstride[1] = 0;
      ga.A[2] = nullptr; ga.W[2] = nullptr; ga.wstride[2] = 0;
      ga.A[3] = nullptr; ga.W[3] = nullptr; ga.wstride[3] = 0;
      gemm_mfma<<<dim3(16, 1, 4), 256, 0, stream>>>(ga, 1024, 4, gp);
    }
    conf2_halt<<<128, 256, 0, stream>>>(gp, cb1, cW2, cb2, h_lang, c_lang, ws,
                                        (float)(i + 1));
  }

  finalize<<<(int)((O7 + 255) / 256), 256, 0, stream>>>(ws, vkey, lkey, it,
                                                        (float*)d_out);
}

// Round 4
// 249.138 us; speedup vs baseline: 6.0762x; 1.1649x over previous
//
#include <hip/hip_runtime.h>
#include <hip/hip_bf16.h>

// Sizes (fixed by the reference setup)
constexpr int B  = 128;
constexpr int D  = 1024;
constexpr int NV = 36;
constexpr int NL = 20;
constexpr int TSTEPS = 4;
constexpr int BD = B * D;              // 131072
constexpr float EPS = 0.01f;

// Workspace layout (floats)
constexpr long GP_STRIDE = 524288;         // one partial slot: [128][4096] f32
constexpr long OFF_GP    = 0;              // 4 slots
constexpr long OFF_LBASE = 4 * GP_STRIDE;  // [B,4096]
constexpr long OFF_HATT  = OFF_LBASE + 524288;
constexpr long OFF_CATT  = OFF_HATT + BD;
constexpr long OFF_HLANG = OFF_CATT + BD;
constexpr long OFF_CLANG = OFF_HLANG + BD;
constexpr long OFF_KVS   = OFF_CLANG + BD;
constexpr long OFF_VCTX  = OFF_KVS + BD;
constexpr long OFF_LCTX  = OFF_VCTX + BD;
constexpr long OFF_WGT   = OFF_LCTX + BD;   // [128][64] softmax weights
constexpr long OFF_HL    = OFF_WGT + 8192;
constexpr long OFF_CL    = OFF_HL + BD;
constexpr long OFF_S     = OFF_CL + BD;     // sum of h_lang over steps
constexpr long OFF_ACC   = OFF_S + BD;
constexpr long OFF_SEL   = OFF_ACC + 128;
constexpr long OFF_COST  = OFF_SEL + 128;

typedef float f32x4 __attribute__((ext_vector_type(4)));
typedef short s16x8 __attribute__((ext_vector_type(8)));

__device__ __forceinline__ float sigf(float x) { return 1.f / (1.f + expf(-x)); }

__device__ __forceinline__ short f2bf(float f) {
  __hip_bfloat16 h = __float2bfloat16(f);
  return *reinterpret_cast<short*>(&h);
}

__device__ __forceinline__ f32x4 LD4(const float* p) { return *(const f32x4*)p; }
__device__ __forceinline__ void ST4(float* p, f32x4 v) { *(f32x4*)p = v; }

// ---------------------------------------------------------------------------
// Init
// ---------------------------------------------------------------------------
__global__ __launch_bounds__(256) void init_ws(const float* __restrict__ kv0,
                                               float* __restrict__ ws) {
  int idx = blockIdx.x * 256 + threadIdx.x;
  if (idx < BD) {
    ws[OFF_KVS + idx] = kv0[idx];
    ws[OFF_HL + idx] = 0.f;
    ws[OFF_CL + idx] = 0.f;
    ws[OFF_S + idx]  = 0.f;
  }
  if (idx < B) {
    ws[OFF_ACC + idx]  = 0.f;
    ws[OFF_SEL + idx]  = 1.f;
    ws[OFF_COST + idx] = 0.f;
  }
}

// ---------------------------------------------------------------------------
// MFMA bf16 GEMM, K-split into 4 partial slots, async-STAGE (T14).
// grid (N/64, 2, 4); block 256 = 4 waves; tile BM=64 BN=64 BK=64.
// z selects {A ptr, W ptr, wstride}; koff folded into the pointers.
// partial[z][128][N] = A_z[64-row tile] @ W_z^T
// Staging: 64 rows x 16 float4-cols = 1024 float4 per array -> 4 iters/thread.
// ---------------------------------------------------------------------------
struct GemmArgs {
  const float* A[4];   // row stride 1024 (col offset folded in)
  const float* W[4];   // row stride wstride (col offset folded in)
  long wstride[4];
  int klen;            // K per z (multiple of 64)
};

__global__ __launch_bounds__(256) void gemm_mfma(GemmArgs ga, int N,
                                                 float* __restrict__ gpart) {
  const int z = blockIdx.z;
  const float* __restrict__ A = ga.A[z];
  const float* __restrict__ W = ga.W[z];
  const long wstr = ga.wstride[z];
  const int brow = blockIdx.y * 64;
  const int bcol = blockIdx.x * 64;
  float* __restrict__ out = gpart + (long)z * GP_STRIDE;

  __shared__ __align__(16) short As[64][72];
  __shared__ __align__(16) short Bs[64][72];

  const int tid = threadIdx.x;
  const int wave = tid >> 6, lane = tid & 63;
  const int wr = wave >> 1, wc = wave & 1;
  const int lrow = lane & 15;
  const int lk8  = (lane >> 4) * 8;

  // staging map: row = (tid>>4) + i*16, col4 = (tid&15)*4  (i = 0..3)
  const int sr = tid >> 4;
  const int sc4 = (tid & 15) * 4;

  f32x4 acc[2][2];
#pragma unroll
  for (int m = 0; m < 2; ++m)
#pragma unroll
    for (int n = 0; n < 2; ++n) acc[m][n] = (f32x4){0.f, 0.f, 0.f, 0.f};

  float4 ra[4], rw[4];
#define LOAD_TILE(KT)                                                          \
  {                                                                            \
    const int kb = (KT) * 64;                                                  \
    _Pragma("unroll") for (int i = 0; i < 4; ++i) {                            \
      const int r = sr + i * 16;                                               \
      ra[i] = *(const float4*)(A + (long)(brow + r) * 1024 + kb + sc4);        \
      rw[i] = *(const float4*)(W + (long)(bcol + r) * wstr + kb + sc4);        \
    }                                                                          \
  }
#define WRITE_TILE()                                                           \
  {                                                                            \
    _Pragma("unroll") for (int i = 0; i < 4; ++i) {                            \
      const int r = sr + i * 16;                                               \
      *(short4*)(&As[r][sc4]) =                                                \
          short4{f2bf(ra[i].x), f2bf(ra[i].y), f2bf(ra[i].z), f2bf(ra[i].w)};  \
      *(short4*)(&Bs[r][sc4]) =                                                \
          short4{f2bf(rw[i].x), f2bf(rw[i].y), f2bf(rw[i].z), f2bf(rw[i].w)};  \
    }                                                                          \
  }

  const int ntiles = ga.klen / 64;
  LOAD_TILE(0);
  for (int kt = 0; kt < ntiles; ++kt) {
    WRITE_TILE();
    __syncthreads();
    if (kt + 1 < ntiles) LOAD_TILE(kt + 1);  // in flight during MFMA phase
    s16x8 af[2], bf[2];
#pragma unroll
    for (int kk = 0; kk < 64; kk += 32) {
#pragma unroll
      for (int m = 0; m < 2; ++m)
        af[m] = *(const s16x8*)(&As[wr * 32 + m * 16 + lrow][kk + lk8]);
#pragma unroll
      for (int n = 0; n < 2; ++n)
        bf[n] = *(const s16x8*)(&Bs[wc * 32 + n * 16 + lrow][kk + lk8]);
#pragma unroll
      for (int m = 0; m < 2; ++m)
#pragma unroll
        for (int n = 0; n < 2; ++n)
          acc[m][n] = __builtin_amdgcn_mfma_f32_16x16x32_bf16(
              af[m], bf[n], acc[m][n], 0, 0, 0);
    }
    __syncthreads();
  }
#undef LOAD_TILE
#undef WRITE_TILE

  // C/D layout: col=lane&15, row=(lane>>4)*4+reg (verified mapping)
#pragma unroll
  for (int m = 0; m < 2; ++m) {
#pragma unroll
    for (int n = 0; n < 2; ++n) {
      const int col = bcol + wc * 32 + n * 16 + lrow;
#pragma unroll
      for (int r = 0; r < 4; ++r) {
        const int row = brow + wr * 32 + m * 16 + (lane >> 4) * 4 + r;
        out[(long)row * N + col] = acc[m][n][r];
      }
    }
  }
}

// ---------------------------------------------------------------------------
// LSTM cell: gates = sum of 4 partials (+extra) (+bih+bhh); i,f,g,o -> h,c
// float4; grid 128 x 256
// ---------------------------------------------------------------------------
__global__ __launch_bounds__(256) void lstm_cell(
    const float* __restrict__ gp, const float* __restrict__ extra,
    const float* __restrict__ bih, const float* __restrict__ bhh,
    const float* __restrict__ c_prev, float* __restrict__ h,
    float* __restrict__ c) {
  long idx = ((long)blockIdx.x * 256 + threadIdx.x) * 4;
  if (idx >= BD) return;
  int b = (int)(idx >> 10), d = (int)(idx & 1023);
  const long base = (long)b * 4096 + d;
  f32x4 g[4];
#pragma unroll
  for (int gi = 0; gi < 4; ++gi) {
    const long o = base + gi * 1024;
    f32x4 v = LD4(gp + o) + LD4(gp + GP_STRIDE + o) + LD4(gp + 2 * GP_STRIDE + o) +
              LD4(gp + 3 * GP_STRIDE + o);
    if (extra) v += LD4(extra + o);
    if (bih) v += LD4(bih + gi * 1024 + d) + LD4(bhh + gi * 1024 + d);
    g[gi] = v;
  }
  f32x4 cp = LD4(c_prev + idx), cc, hh;
#pragma unroll
  for (int j = 0; j < 4; ++j) {
    float ccj = sigf(g[1][j]) * cp[j] + sigf(g[0][j]) * tanhf(g[2][j]);
    cc[j] = ccj;
    hh[j] = sigf(g[3][j]) * tanhf(ccj);
  }
  ST4(c + idx, cc);
  ST4(h + idx, hh);
}

// ---------------------------------------------------------------------------
// reduce4: out = p0+p1+p2+p3 + bih + bhh   (float4; grid 512)
// ---------------------------------------------------------------------------
__global__ __launch_bounds__(256) void reduce4(
    const float* __restrict__ gp, const float* __restrict__ bih,
    const float* __restrict__ bhh, float* __restrict__ out) {
  long idx = ((long)blockIdx.x * 256 + threadIdx.x) * 4;
  if (idx >= (long)B * 4096) return;
  int col = (int)(idx & 4095);
  f32x4 v = LD4(gp + idx) + LD4(gp + GP_STRIDE + idx) +
            LD4(gp + 2 * GP_STRIDE + idx) + LD4(gp + 3 * GP_STRIDE + idx) +
            LD4(bih + col) + LD4(bhh + col);
  ST4(out + idx, v);
}

// ---------------------------------------------------------------------------
// Attention logits + softmax (update cancels in softmax -> original keys).
// ---------------------------------------------------------------------------
__global__ __launch_bounds__(256) void attn_logits(
    const float* __restrict__ h_att, const float* __restrict__ kvs,
    const float* __restrict__ vkey, const float* __restrict__ lkey,
    float* __restrict__ wgt_out) {
  const int b = blockIdx.x, tid = threadIdx.x;
  __shared__ float q[1024];
  __shared__ float wgt[64];
  for (int d = tid; d < 1024; d += 256)
    q[d] = h_att[(long)b * 1024 + d] + kvs[(long)b * 1024 + d];
  __syncthreads();

  const int wave = tid >> 6, lane = tid & 63;
  for (int n = wave; n < NV + NL; n += 4) {
    const float* key = (n < NV) ? (vkey + ((long)b * NV + n) * 1024)
                                : (lkey + ((long)b * NL + (n - NV)) * 1024);
    float s = 0.f;
#pragma unroll
    for (int j = 0; j < 4; ++j) {
      f32x4 k4 = LD4(key + lane * 4 + j * 256);
      f32x4 q4 = *(const f32x4*)(&q[lane * 4 + j * 256]);
      s += k4[0] * q4[0] + k4[1] * q4[1] + k4[2] * q4[2] + k4[3] * q4[3];
    }
    for (int m = 32; m >= 1; m >>= 1) s += __shfl_xor(s, m);
    if (lane == 0) wgt[n] = s * (1.0f / 32.0f);
  }
  __syncthreads();

  if (wave == 0) {
    float x = (lane < NV) ? wgt[lane] : -1e30f;
    float m = x;
    for (int k = 32; k >= 1; k >>= 1) m = fmaxf(m, __shfl_xor(m, k));
    float e = (lane < NV) ? expf(x - m) : 0.f;
    float ssum = e;
    for (int k = 32; k >= 1; k >>= 1) ssum += __shfl_xor(ssum, k);
    if (lane < NV) wgt_out[b * 64 + lane] = e / ssum;
  } else if (wave == 1) {
    float x = (lane < NL) ? wgt[NV + lane] : -1e30f;
    float m = x;
    for (int k = 32; k >= 1; k >>= 1) m = fmaxf(m, __shfl_xor(m, k));
    float e = (lane < NL) ? expf(x - m) : 0.f;
    float ssum = e;
    for (int k = 32; k >= 1; k >>= 1) ssum += __shfl_xor(ssum, k);
    if (lane < NL) wgt_out[b * 64 + NV + lane] = e / ssum;
  }
}

// ---------------------------------------------------------------------------
// Attention context + kvs update. grid (128, 2) x 256; float2 per thread.
// ---------------------------------------------------------------------------
__global__ __launch_bounds__(256) void attn_ctx(
    const float* __restrict__ wgt, const float* __restrict__ vval,
    const float* __restrict__ lval, float* __restrict__ kvs,
    float* __restrict__ vctx, float* __restrict__ lctx) {
  const int b = blockIdx.x, half = blockIdx.y, tid = threadIdx.x;
  __shared__ float w[64];
  if (tid < NV + NL) w[tid] = wgt[b * 64 + tid];
  __syncthreads();
  const int d = half * 512 + tid * 2;
  float vcx = 0.f, vcy = 0.f, lcx = 0.f, lcy = 0.f;
  const float* vp = vval + (long)b * NV * 1024 + d;
#pragma unroll 6
  for (int n = 0; n < NV; ++n) {
    float2 v = *(const float2*)(vp + (long)n * 1024);
    vcx += w[n] * v.x;
    vcy += w[n] * v.y;
  }
  const float* lp = lval + (long)b * NL * 1024 + d;
#pragma unroll 5
  for (int n = 0; n < NL; ++n) {
    float2 v = *(const float2*)(lp + (long)n * 1024);
    lcx += w[NV + n] * v.x;
    lcy += w[NV + n] * v.y;
  }
  const long i = (long)b * 1024 + d;
  vctx[i] = vcx; vctx[i + 1] = vcy;
  lctx[i] = lcx; lctx[i + 1] = lcy;
  kvs[i]     = tanhf(kvs[i] + vcx + lcx);
  kvs[i + 1] = tanhf(kvs[i + 1] + vcy + lcy);
}

// ---------------------------------------------------------------------------
// Confidence (4 partials [128][1024] -> relu -> dot W2 -> sigmoid) + halting.
// ---------------------------------------------------------------------------
__global__ __launch_bounds__(256) void conf2_halt(
    const float* __restrict__ gp, const float* __restrict__ cb1,
    const float* __restrict__ W2, const float* __restrict__ b2,
    const float* __restrict__ h_lang, const float* __restrict__ c_lang,
    float* __restrict__ ws, float stepnum) {
  const int b = blockIdx.x, tid = threadIdx.x;
  __shared__ float red[256];
  __shared__ float p_sh;
  const int d0 = tid * 4;
  const long o = (long)b * 1024 + d0;
  f32x4 rv = LD4(gp + o) + LD4(gp + GP_STRIDE + o) + LD4(gp + 2 * GP_STRIDE + o) +
             LD4(gp + 3 * GP_STRIDE + o) + LD4(cb1 + d0);
  f32x4 w4 = LD4(W2 + d0);
  float part = 0.f;
#pragma unroll
  for (int j = 0; j < 4; ++j) part += fmaxf(rv[j], 0.f) * w4[j];
  red[tid] = part;
  __syncthreads();
  for (int s = 128; s > 0; s >>= 1) {
    if (tid < s) red[tid] += red[tid + s];
    __syncthreads();
  }
  if (tid == 0) p_sh = sigf(red[0] + b2[0]);
  __syncthreads();
  const float p = p_sh;
  const float a_old = ws[OFF_ACC + b];
  const float s_old = ws[OFF_SEL + b];
  const float bs = p * (1.f - a_old) * s_old;
  {
    const long i = (long)b * 1024 + d0;
    f32x4 hl = LD4(h_lang + i), cl = LD4(c_lang + i);
    ST4(ws + OFF_HL + i, LD4(ws + OFF_HL + i) + hl * bs);
    ST4(ws + OFF_CL + i, LD4(ws + OFF_CL + i) + cl * bs);
    ST4(ws + OFF_S + i, LD4(ws + OFF_S + i) + hl);  // key update unmasked
  }
  if (tid == 0) {
    ws[OFF_COST + b] += stepnum * (1.f - p) * s_old;
    const float a_new = a_old + bs;
    ws[OFF_ACC + b] = a_new;
    ws[OFF_SEL + b] = (a_new < 1.f - EPS) ? s_old : 0.f;
  }
}

// ---------------------------------------------------------------------------
// Final output assembly (float4).
// ---------------------------------------------------------------------------
constexpr long O1 = BD;
constexpr long O2 = O1 + (long)B * NV * D;
constexpr long O3 = O2 + (long)B * NL * D;
constexpr long O4 = O3 + B;
constexpr long O5 = O4 + 2L * BD;
constexpr long O6 = O5 + 2L * BD;
constexpr long O7 = O6 + BD;

__global__ __launch_bounds__(256) void finalize(
    const float* __restrict__ ws, const float* __restrict__ vkey0,
    const float* __restrict__ lkey0, const int* __restrict__ it,
    float* __restrict__ out) {
  long idx = ((long)blockIdx.x * 256 + threadIdx.x) * 4;
  if (idx >= O7) return;
  if (idx < O1) {
    int b = (int)(idx >> 10);
    ST4(out + idx, LD4(ws + OFF_HL + idx) * (1.f / ws[OFF_ACC + b]));
  } else if (idx < O2) {
    long r = idx - O1;
    int b = (int)(r / (NV * 1024));
    int d = (int)(r & 1023);
    ST4(out + idx, LD4(vkey0 + r) + LD4(ws + OFF_S + (long)b * 1024 + d) * 0.01f);
  } else if (idx < O3) {
    long r = idx - O2;
    int b = (int)(r / (NL * 1024));
    int d = (int)(r & 1023);
    ST4(out + idx, LD4(lkey0 + r) + LD4(ws + OFF_S + (long)b * 1024 + d) * 0.01f);
  } else if (idx < O4) {
#pragma unroll
    for (int j = 0; j < 4; ++j) {
      int b = (int)(idx + j - O3);
      out[idx + j] = ws[OFF_COST + b] * ((it[b] > 0) ? 1.f : 0.f);
    }
  } else if (idx < O5) {
    long r = idx - O4;
    if (r < BD) {
      ST4(out + idx, LD4(ws + OFF_HATT + r));       // hA/accum == h_att
    } else {
      long q2 = r - BD;
      int b = (int)(q2 >> 10);
      ST4(out + idx, LD4(ws + OFF_HL + q2) * (1.f / ws[OFF_ACC + b]));
    }
  } else if (idx < O6) {
    long r = idx - O5;
    if (r < BD) {
      ST4(out + idx, LD4(ws + OFF_CATT + r));       // cA/accum == c_att
    } else {
      long q2 = r - BD;
      int b = (int)(q2 >> 10);
      ST4(out + idx, LD4(ws + OFF_CL + q2) * (1.f / ws[OFF_ACC + b]));
    }
  } else {
    ST4(out + idx, LD4(ws + OFF_KVS + (idx - O6)));
  }
}

// ---------------------------------------------------------------------------
extern "C" void kernel_launch(void* const* d_in, const int* in_sizes, int n_in,
                              void* d_out, int out_size, void* d_ws, size_t ws_size,
                              hipStream_t stream) {
  const float* xt   = (const float*)d_in[0];
  const int*   it   = (const int*)d_in[1];
  const float* fc   = (const float*)d_in[2];
  const float* vval = (const float*)d_in[3];
  const float* vkey = (const float*)d_in[4];
  const float* lval = (const float*)d_in[5];
  const float* lkey = (const float*)d_in[6];
  const float* kv0  = (const float*)d_in[7];
  const float* sh   = (const float*)d_in[8];   // [2,B,D]
  const float* sc   = (const float*)d_in[9];   // [2,B,D]
  // d_in[10] = max_att_step (4)
  const float* aWih = (const float*)d_in[11];  // [4096,3072]
  const float* aWhh = (const float*)d_in[12];  // [4096,1024]
  const float* abih = (const float*)d_in[13];
  const float* abhh = (const float*)d_in[14];
  const float* lWih = (const float*)d_in[15];  // [4096,3072]
  const float* lWhh = (const float*)d_in[16];  // [4096,1024]
  const float* lbih = (const float*)d_in[17];
  const float* lbhh = (const float*)d_in[18];
  const float* cW1  = (const float*)d_in[19];  // [1024,1024]
  const float* cb1  = (const float*)d_in[20];
  const float* cW2  = (const float*)d_in[21];  // [1,1024]
  const float* cb2  = (const float*)d_in[22];

  float* ws = (float*)d_ws;
  float* gp     = ws + OFF_GP;
  float* lbase  = ws + OFF_LBASE;
  float* h_att  = ws + OFF_HATT;
  float* c_att  = ws + OFF_CATT;
  float* h_lang = ws + OFF_HLANG;
  float* c_lang = ws + OFF_CLANG;
  float* kvs    = ws + OFF_KVS;
  float* vctx   = ws + OFF_VCTX;
  float* lctx   = ws + OFF_LCTX;
  float* wgt    = ws + OFF_WGT;

  const float* sh1 = sh + BD;  // state_h[1]
  const float* sc0 = sc;       // state_c[0]
  const float* sc1 = sc + BD;  // state_c[1]

  init_ws<<<512, 256, 0, stream>>>(kv0, ws);

  // att gates: [sh1,fc,xt]@aWih^T + sh0@aWhh^T  -> slots 0..3 (z = chunk)
  {
    GemmArgs ga;
    ga.A[0] = sh1; ga.W[0] = aWih;        ga.wstride[0] = 3072;
    ga.A[1] = fc;  ga.W[1] = aWih + 1024; ga.wstride[1] = 3072;
    ga.A[2] = xt;  ga.W[2] = aWih + 2048; ga.wstride[2] = 3072;
    ga.A[3] = sh;  ga.W[3] = aWhh;        ga.wstride[3] = 1024;
    ga.klen = 1024;
    gemm_mfma<<<dim3(64, 2, 4), 256, 0, stream>>>(ga, 4096, gp);
  }
  lstm_cell<<<128, 256, 0, stream>>>(gp, nullptr, abih, abhh, sc0, h_att, c_att);

  // lbase: sh1@lWhh^T + h_att@lWih[:,2048:]^T (K halves -> 4 slots)
  {
    GemmArgs ga;
    ga.A[0] = sh1;         ga.W[0] = lWhh;              ga.wstride[0] = 1024;
    ga.A[1] = sh1 + 512;   ga.W[1] = lWhh + 512;        ga.wstride[1] = 1024;
    ga.A[2] = h_att;       ga.W[2] = lWih + 2048;       ga.wstride[2] = 3072;
    ga.A[3] = h_att + 512; ga.W[3] = lWih + 2048 + 512; ga.wstride[3] = 3072;
    ga.klen = 512;
    gemm_mfma<<<dim3(64, 2, 4), 256, 0, stream>>>(ga, 4096, gp);
  }
  reduce4<<<512, 256, 0, stream>>>(gp, lbih, lbhh, lbase);

  for (int i = 0; i < TSTEPS; ++i) {
    attn_logits<<<128, 256, 0, stream>>>(h_att, kvs, vkey, lkey, wgt);
    attn_ctx<<<dim3(128, 2), 256, 0, stream>>>(wgt, vval, lval, kvs, vctx, lctx);
    {
      GemmArgs ga;
      ga.A[0] = vctx;       ga.W[0] = lWih;              ga.wstride[0] = 3072;
      ga.A[1] = vctx + 512; ga.W[1] = lWih + 512;        ga.wstride[1] = 3072;
      ga.A[2] = lctx;       ga.W[2] = lWih + 1024;       ga.wstride[2] = 3072;
      ga.A[3] = lctx + 512; ga.W[3] = lWih + 1024 + 512; ga.wstride[3] = 3072;
      ga.klen = 512;
      gemm_mfma<<<dim3(64, 2, 4), 256, 0, stream>>>(ga, 4096, gp);
    }
    lstm_cell<<<128, 256, 0, stream>>>(gp, lbase, nullptr, nullptr, sc1,
                                       h_lang, c_lang);
    {
      GemmArgs ga;
#pragma unroll
      for (int z = 0; z < 4; ++z) {
        ga.A[z] = h_lang + z * 256;
        ga.W[z] = cW1 + z * 256;
        ga.wstride[z] = 1024;
      }
      ga.klen = 256;
      gemm_mfma<<<dim3(16, 2, 4), 256, 0, stream>>>(ga, 1024, gp);
    }
    conf2_halt<<<128, 256, 0, stream>>>(gp, cb1, cW2, cb2, h_lang, c_lang, ws,
                                        (float)(i + 1));
  }

  finalize<<<(int)((O7 / 4 + 255) / 256), 256, 0, stream>>>(ws, vkey, lkey, it,
                                                            (float*)d_out);
}

// Round 5
// 248.056 us; speedup vs baseline: 6.1027x; 1.0044x over previous
//
#include <hip/hip_runtime.h>
#include <hip/hip_bf16.h>

// Sizes (fixed by the reference setup)
constexpr int B  = 128;
constexpr int D  = 1024;
constexpr int NV = 36;
constexpr int NL = 20;
constexpr int TSTEPS = 4;
constexpr int BD = B * D;              // 131072
constexpr float EPS = 0.01f;
constexpr int NSLOT = 8;               // split-K partial slots

// Workspace layout (floats)
constexpr long GP_STRIDE = 524288;            // one partial slot: [128][4096] f32
constexpr long OFF_GP    = 0;                 // 8 slots
constexpr long OFF_LBASE = NSLOT * GP_STRIDE; // [B,4096]
constexpr long OFF_HATT  = OFF_LBASE + 524288;
constexpr long OFF_CATT  = OFF_HATT + BD;
constexpr long OFF_HLANG = OFF_CATT + BD;
constexpr long OFF_CLANG = OFF_HLANG + BD;
constexpr long OFF_KVS   = OFF_CLANG + BD;
constexpr long OFF_VCTX  = OFF_KVS + BD;
constexpr long OFF_LCTX  = OFF_VCTX + BD;
constexpr long OFF_HL    = OFF_LCTX + BD;
constexpr long OFF_CL    = OFF_HL + BD;
constexpr long OFF_S     = OFF_CL + BD;       // sum of h_lang over steps
constexpr long OFF_ACC   = OFF_S + BD;
constexpr long OFF_SEL   = OFF_ACC + 128;
constexpr long OFF_COST  = OFF_SEL + 128;

typedef float f32x4 __attribute__((ext_vector_type(4)));
typedef short s16x8 __attribute__((ext_vector_type(8)));

__device__ __forceinline__ float sigf(float x) { return 1.f / (1.f + expf(-x)); }

__device__ __forceinline__ short f2bf(float f) {
  __hip_bfloat16 h = __float2bfloat16(f);
  return *reinterpret_cast<short*>(&h);
}

__device__ __forceinline__ f32x4 LD4(const float* p) { return *(const f32x4*)p; }
__device__ __forceinline__ void ST4(float* p, f32x4 v) { *(f32x4*)p = v; }

// ---------------------------------------------------------------------------
// Init
// ---------------------------------------------------------------------------
__global__ __launch_bounds__(256) void init_ws(const float* __restrict__ kv0,
                                               float* __restrict__ ws) {
  int idx = blockIdx.x * 256 + threadIdx.x;
  if (idx < BD) {
    ws[OFF_KVS + idx] = kv0[idx];
    ws[OFF_HL + idx] = 0.f;
    ws[OFF_CL + idx] = 0.f;
    ws[OFF_S + idx]  = 0.f;
  }
  if (idx < B) {
    ws[OFF_ACC + idx]  = 0.f;
    ws[OFF_SEL + idx]  = 1.f;
    ws[OFF_COST + idx] = 0.f;
  }
}

// ---------------------------------------------------------------------------
// MFMA bf16 GEMM, 8-way split-K partials, double-buffered LDS (one barrier
// per k-tile), 1-deep register prefetch of the next tile's global loads.
// grid (N/64, 2, 8); block 256 = 4 waves; tile BM=64 BN=64 BK=64.
// partial[z][128][N] = A_z @ W_z^T   (z-chunk pointers pre-offset)
// ---------------------------------------------------------------------------
struct GemmArgs {
  const float* A[NSLOT];   // row stride 1024 (col offset folded in)
  const float* W[NSLOT];   // row stride wstride (col offset folded in)
  long wstride[NSLOT];
  int klen;                // K per z (multiple of 64)
};

__global__ __launch_bounds__(256, 4) void gemm_mfma(GemmArgs ga, int N,
                                                    float* __restrict__ gpart) {
  const int z = blockIdx.z;
  const float* __restrict__ A = ga.A[z];
  const float* __restrict__ W = ga.W[z];
  const long wstr = ga.wstride[z];
  const int brow = blockIdx.y * 64;
  const int bcol = blockIdx.x * 64;
  float* __restrict__ out = gpart + (long)z * GP_STRIDE;

  __shared__ __align__(16) short As[2][64][72];
  __shared__ __align__(16) short Bs[2][64][72];

  const int tid = threadIdx.x;
  const int wave = tid >> 6, lane = tid & 63;
  const int wr = wave >> 1, wc = wave & 1;
  const int lrow = lane & 15;
  const int lk8  = (lane >> 4) * 8;

  // staging map: row = (tid>>4) + i*16, col4 = (tid&15)*4  (i = 0..3)
  const int sr = tid >> 4;
  const int sc4 = (tid & 15) * 4;

  f32x4 acc[2][2];
#pragma unroll
  for (int m = 0; m < 2; ++m)
#pragma unroll
    for (int n = 0; n < 2; ++n) acc[m][n] = (f32x4){0.f, 0.f, 0.f, 0.f};

  float4 ra[4], rw[4];
#define LOAD_TILE(KT)                                                          \
  {                                                                            \
    const int kb = (KT) * 64;                                                  \
    _Pragma("unroll") for (int i = 0; i < 4; ++i) {                            \
      const int r = sr + i * 16;                                               \
      ra[i] = *(const float4*)(A + (long)(brow + r) * 1024 + kb + sc4);        \
      rw[i] = *(const float4*)(W + (long)(bcol + r) * wstr + kb + sc4);        \
    }                                                                          \
  }
#define WRITE_TILE(BUF)                                                        \
  {                                                                            \
    _Pragma("unroll") for (int i = 0; i < 4; ++i) {                            \
      const int r = sr + i * 16;                                               \
      *(short4*)(&As[BUF][r][sc4]) =                                           \
          short4{f2bf(ra[i].x), f2bf(ra[i].y), f2bf(ra[i].z), f2bf(ra[i].w)};  \
      *(short4*)(&Bs[BUF][r][sc4]) =                                           \
          short4{f2bf(rw[i].x), f2bf(rw[i].y), f2bf(rw[i].z), f2bf(rw[i].w)};  \
    }                                                                          \
  }

  const int ntiles = ga.klen / 64;
  LOAD_TILE(0);
  WRITE_TILE(0);
  __syncthreads();
  for (int kt = 0; kt < ntiles; ++kt) {
    const int cur = kt & 1;
    const bool more = (kt + 1 < ntiles);
    if (more) LOAD_TILE(kt + 1);  // global loads in flight during MFMA phase
    s16x8 af[2], bf[2];
#pragma unroll
    for (int kk = 0; kk < 64; kk += 32) {
#pragma unroll
      for (int m = 0; m < 2; ++m)
        af[m] = *(const s16x8*)(&As[cur][wr * 32 + m * 16 + lrow][kk + lk8]);
#pragma unroll
      for (int n = 0; n < 2; ++n)
        bf[n] = *(const s16x8*)(&Bs[cur][wc * 32 + n * 16 + lrow][kk + lk8]);
#pragma unroll
      for (int m = 0; m < 2; ++m)
#pragma unroll
        for (int n = 0; n < 2; ++n)
          acc[m][n] = __builtin_amdgcn_mfma_f32_16x16x32_bf16(
              af[m], bf[n], acc[m][n], 0, 0, 0);
    }
    if (more) WRITE_TILE(1 - cur);  // safe: buf consumed at kt-1, sync passed
    __syncthreads();
  }
#undef LOAD_TILE
#undef WRITE_TILE

  // C/D layout: col=lane&15, row=(lane>>4)*4+reg (verified mapping)
#pragma unroll
  for (int m = 0; m < 2; ++m) {
#pragma unroll
    for (int n = 0; n < 2; ++n) {
      const int col = bcol + wc * 32 + n * 16 + lrow;
#pragma unroll
      for (int r = 0; r < 4; ++r) {
        const int row = brow + wr * 32 + m * 16 + (lane >> 4) * 4 + r;
        out[(long)row * N + col] = acc[m][n][r];
      }
    }
  }
}

// ---------------------------------------------------------------------------
// LSTM cell: gates = sum of 8 partials (+extra) (+bih+bhh); i,f,g,o -> h,c
// ---------------------------------------------------------------------------
__global__ __launch_bounds__(256) void lstm_cell(
    const float* __restrict__ gp, const float* __restrict__ extra,
    const float* __restrict__ bih, const float* __restrict__ bhh,
    const float* __restrict__ c_prev, float* __restrict__ h,
    float* __restrict__ c) {
  long idx = ((long)blockIdx.x * 256 + threadIdx.x) * 4;
  if (idx >= BD) return;
  int b = (int)(idx >> 10), d = (int)(idx & 1023);
  const long base = (long)b * 4096 + d;
  f32x4 g[4];
#pragma unroll
  for (int gi = 0; gi < 4; ++gi) {
    const long o = base + gi * 1024;
    f32x4 v = (f32x4){0.f, 0.f, 0.f, 0.f};
#pragma unroll
    for (int s = 0; s < NSLOT; ++s) v += LD4(gp + s * GP_STRIDE + o);
    if (extra) v += LD4(extra + o);
    if (bih) v += LD4(bih + gi * 1024 + d) + LD4(bhh + gi * 1024 + d);
    g[gi] = v;
  }
  f32x4 cp = LD4(c_prev + idx), cc, hh;
#pragma unroll
  for (int j = 0; j < 4; ++j) {
    float ccj = sigf(g[1][j]) * cp[j] + sigf(g[0][j]) * tanhf(g[2][j]);
    cc[j] = ccj;
    hh[j] = sigf(g[3][j]) * tanhf(ccj);
  }
  ST4(c + idx, cc);
  ST4(h + idx, hh);
}

// ---------------------------------------------------------------------------
// reduce8: out = sum of 8 partials + bih + bhh   (for lbase)
// ---------------------------------------------------------------------------
__global__ __launch_bounds__(256) void reduce8(
    const float* __restrict__ gp, const float* __restrict__ bih,
    const float* __restrict__ bhh, float* __restrict__ out) {
  long idx = ((long)blockIdx.x * 256 + threadIdx.x) * 4;
  if (idx >= (long)B * 4096) return;
  int col = (int)(idx & 4095);
  f32x4 v = LD4(bih + col) + LD4(bhh + col);
#pragma unroll
  for (int s = 0; s < NSLOT; ++s) v += LD4(gp + s * GP_STRIDE + idx);
  ST4(out + idx, v);
}

// ---------------------------------------------------------------------------
// Fused attention: logits (original keys; slot-uniform update cancels in
// softmax) + softmax + context + kvs update. One block per batch element.
// ---------------------------------------------------------------------------
__global__ __launch_bounds__(256) void attn_fused(
    const float* __restrict__ h_att, float* __restrict__ kvs,
    const float* __restrict__ vkey, const float* __restrict__ lkey,
    const float* __restrict__ vval, const float* __restrict__ lval,
    float* __restrict__ vctx, float* __restrict__ lctx) {
  const int b = blockIdx.x, tid = threadIdx.x;
  __shared__ float q[1024];
  __shared__ float wgt[64];
  {
    const int d = tid * 4;
    ST4(q + d, LD4(h_att + (long)b * 1024 + d) + LD4(kvs + (long)b * 1024 + d));
  }
  __syncthreads();

  const int wave = tid >> 6, lane = tid & 63;
  for (int n = wave; n < NV + NL; n += 4) {
    const float* key = (n < NV) ? (vkey + ((long)b * NV + n) * 1024)
                                : (lkey + ((long)b * NL + (n - NV)) * 1024);
    float s = 0.f;
#pragma unroll
    for (int j = 0; j < 4; ++j) {
      f32x4 k4 = LD4(key + lane * 4 + j * 256);
      f32x4 q4 = *(const f32x4*)(&q[lane * 4 + j * 256]);
      s += k4[0] * q4[0] + k4[1] * q4[1] + k4[2] * q4[2] + k4[3] * q4[3];
    }
    for (int m = 32; m >= 1; m >>= 1) s += __shfl_xor(s, m);
    if (lane == 0) wgt[n] = s * (1.0f / 32.0f);
  }
  __syncthreads();

  if (wave == 0) {
    float x = (lane < NV) ? wgt[lane] : -1e30f;
    float m = x;
    for (int k = 32; k >= 1; k >>= 1) m = fmaxf(m, __shfl_xor(m, k));
    float e = (lane < NV) ? expf(x - m) : 0.f;
    float ssum = e;
    for (int k = 32; k >= 1; k >>= 1) ssum += __shfl_xor(ssum, k);
    if (lane < NV) wgt[lane] = e / ssum;
  } else if (wave == 1) {
    float x = (lane < NL) ? wgt[NV + lane] : -1e30f;
    float m = x;
    for (int k = 32; k >= 1; k >>= 1) m = fmaxf(m, __shfl_xor(m, k));
    float e = (lane < NL) ? expf(x - m) : 0.f;
    float ssum = e;
    for (int k = 32; k >= 1; k >>= 1) ssum += __shfl_xor(ssum, k);
    if (lane < NL) wgt[NV + lane] = e / ssum;
  }
  __syncthreads();

  // context: thread t handles 4 consecutive d-cols
  const int d = tid * 4;
  f32x4 vc = (f32x4){0.f, 0.f, 0.f, 0.f}, lc = vc;
  const float* vp = vval + (long)b * NV * 1024 + d;
#pragma unroll 6
  for (int n = 0; n < NV; ++n) vc += LD4(vp + (long)n * 1024) * wgt[n];
  const float* lp = lval + (long)b * NL * 1024 + d;
#pragma unroll 5
  for (int n = 0; n < NL; ++n) lc += LD4(lp + (long)n * 1024) * wgt[NV + n];
  const long i = (long)b * 1024 + d;
  ST4(vctx + i, vc);
  ST4(lctx + i, lc);
  f32x4 kv = LD4(kvs + i) + vc + lc;
#pragma unroll
  for (int j = 0; j < 4; ++j) kv[j] = tanhf(kv[j]);
  ST4(kvs + i, kv);
}

// ---------------------------------------------------------------------------
// Confidence (8 partials [128][1024] -> relu -> dot W2 -> sigmoid) + halting.
// ---------------------------------------------------------------------------
__global__ __launch_bounds__(256) void conf2_halt(
    const float* __restrict__ gp, const float* __restrict__ cb1,
    const float* __restrict__ W2, const float* __restrict__ b2,
    const float* __restrict__ h_lang, const float* __restrict__ c_lang,
    float* __restrict__ ws, float stepnum) {
  const int b = blockIdx.x, tid = threadIdx.x;
  __shared__ float red[256];
  __shared__ float p_sh;
  const int d0 = tid * 4;
  const long o = (long)b * 1024 + d0;
  f32x4 rv = LD4(cb1 + d0);
#pragma unroll
  for (int s = 0; s < NSLOT; ++s) rv += LD4(gp + s * GP_STRIDE + o);
  f32x4 w4 = LD4(W2 + d0);
  float part = 0.f;
#pragma unroll
  for (int j = 0; j < 4; ++j) part += fmaxf(rv[j], 0.f) * w4[j];
  red[tid] = part;
  __syncthreads();
  for (int s = 128; s > 0; s >>= 1) {
    if (tid < s) red[tid] += red[tid + s];
    __syncthreads();
  }
  if (tid == 0) p_sh = sigf(red[0] + b2[0]);
  __syncthreads();
  const float p = p_sh;
  const float a_old = ws[OFF_ACC + b];
  const float s_old = ws[OFF_SEL + b];
  const float bs = p * (1.f - a_old) * s_old;
  {
    const long i = (long)b * 1024 + d0;
    f32x4 hl = LD4(h_lang + i), cl = LD4(c_lang + i);
    ST4(ws + OFF_HL + i, LD4(ws + OFF_HL + i) + hl * bs);
    ST4(ws + OFF_CL + i, LD4(ws + OFF_CL + i) + cl * bs);
    ST4(ws + OFF_S + i, LD4(ws + OFF_S + i) + hl);  // key update unmasked
  }
  if (tid == 0) {
    ws[OFF_COST + b] += stepnum * (1.f - p) * s_old;
    const float a_new = a_old + bs;
    ws[OFF_ACC + b] = a_new;
    ws[OFF_SEL + b] = (a_new < 1.f - EPS) ? s_old : 0.f;
  }
}

// ---------------------------------------------------------------------------
// Final output assembly (float4).
// ---------------------------------------------------------------------------
constexpr long O1 = BD;
constexpr long O2 = O1 + (long)B * NV * D;
constexpr long O3 = O2 + (long)B * NL * D;
constexpr long O4 = O3 + B;
constexpr long O5 = O4 + 2L * BD;
constexpr long O6 = O5 + 2L * BD;
constexpr long O7 = O6 + BD;

__global__ __launch_bounds__(256) void finalize(
    const float* __restrict__ ws, const float* __restrict__ vkey0,
    const float* __restrict__ lkey0, const int* __restrict__ it,
    float* __restrict__ out) {
  long idx = ((long)blockIdx.x * 256 + threadIdx.x) * 4;
  if (idx >= O7) return;
  if (idx < O1) {
    int b = (int)(idx >> 10);
    ST4(out + idx, LD4(ws + OFF_HL + idx) * (1.f / ws[OFF_ACC + b]));
  } else if (idx < O2) {
    long r = idx - O1;
    int b = (int)(r / (NV * 1024));
    int d = (int)(r & 1023);
    ST4(out + idx, LD4(vkey0 + r) + LD4(ws + OFF_S + (long)b * 1024 + d) * 0.01f);
  } else if (idx < O3) {
    long r = idx - O2;
    int b = (int)(r / (NL * 1024));
    int d = (int)(r & 1023);
    ST4(out + idx, LD4(lkey0 + r) + LD4(ws + OFF_S + (long)b * 1024 + d) * 0.01f);
  } else if (idx < O4) {
#pragma unroll
    for (int j = 0; j < 4; ++j) {
      int b = (int)(idx + j - O3);
      out[idx + j] = ws[OFF_COST + b] * ((it[b] > 0) ? 1.f : 0.f);
    }
  } else if (idx < O5) {
    long r = idx - O4;
    if (r < BD) {
      ST4(out + idx, LD4(ws + OFF_HATT + r));       // hA/accum == h_att
    } else {
      long q2 = r - BD;
      int b = (int)(q2 >> 10);
      ST4(out + idx, LD4(ws + OFF_HL + q2) * (1.f / ws[OFF_ACC + b]));
    }
  } else if (idx < O6) {
    long r = idx - O5;
    if (r < BD) {
      ST4(out + idx, LD4(ws + OFF_CATT + r));       // cA/accum == c_att
    } else {
      long q2 = r - BD;
      int b = (int)(q2 >> 10);
      ST4(out + idx, LD4(ws + OFF_CL + q2) * (1.f / ws[OFF_ACC + b]));
    }
  } else {
    ST4(out + idx, LD4(ws + OFF_KVS + (idx - O6)));
  }
}

// ---------------------------------------------------------------------------
extern "C" void kernel_launch(void* const* d_in, const int* in_sizes, int n_in,
                              void* d_out, int out_size, void* d_ws, size_t ws_size,
                              hipStream_t stream) {
  const float* xt   = (const float*)d_in[0];
  const int*   it   = (const int*)d_in[1];
  const float* fc   = (const float*)d_in[2];
  const float* vval = (const float*)d_in[3];
  const float* vkey = (const float*)d_in[4];
  const float* lval = (const float*)d_in[5];
  const float* lkey = (const float*)d_in[6];
  const float* kv0  = (const float*)d_in[7];
  const float* sh   = (const float*)d_in[8];   // [2,B,D]
  const float* sc   = (const float*)d_in[9];   // [2,B,D]
  // d_in[10] = max_att_step (4)
  const float* aWih = (const float*)d_in[11];  // [4096,3072]
  const float* aWhh = (const float*)d_in[12];  // [4096,1024]
  const float* abih = (const float*)d_in[13];
  const float* abhh = (const float*)d_in[14];
  const float* lWih = (const float*)d_in[15];  // [4096,3072]
  const float* lWhh = (const float*)d_in[16];  // [4096,1024]
  const float* lbih = (const float*)d_in[17];
  const float* lbhh = (const float*)d_in[18];
  const float* cW1  = (const float*)d_in[19];  // [1024,1024]
  const float* cb1  = (const float*)d_in[20];
  const float* cW2  = (const float*)d_in[21];  // [1,1024]
  const float* cb2  = (const float*)d_in[22];

  float* ws = (float*)d_ws;
  float* gp     = ws + OFF_GP;
  float* lbase  = ws + OFF_LBASE;
  float* h_att  = ws + OFF_HATT;
  float* c_att  = ws + OFF_CATT;
  float* h_lang = ws + OFF_HLANG;
  float* c_lang = ws + OFF_CLANG;
  float* kvs    = ws + OFF_KVS;
  float* vctx   = ws + OFF_VCTX;
  float* lctx   = ws + OFF_LCTX;

  const float* sh1 = sh + BD;  // state_h[1]
  const float* sc0 = sc;       // state_c[0]
  const float* sc1 = sc + BD;  // state_c[1]

  init_ws<<<512, 256, 0, stream>>>(kv0, ws);

  // att gates: [sh1,fc,xt]@aWih^T + sh0@aWhh^T, each K=1024 pair split in 2
  {
    GemmArgs ga;
    ga.A[0] = sh1;       ga.W[0] = aWih;        ga.wstride[0] = 3072;
    ga.A[1] = sh1 + 512; ga.W[1] = aWih + 512;  ga.wstride[1] = 3072;
    ga.A[2] = fc;        ga.W[2] = aWih + 1024; ga.wstride[2] = 3072;
    ga.A[3] = fc + 512;  ga.W[3] = aWih + 1536; ga.wstride[3] = 3072;
    ga.A[4] = xt;        ga.W[4] = aWih + 2048; ga.wstride[4] = 3072;
    ga.A[5] = xt + 512;  ga.W[5] = aWih + 2560; ga.wstride[5] = 3072;
    ga.A[6] = sh;        ga.W[6] = aWhh;        ga.wstride[6] = 1024;
    ga.A[7] = sh + 512;  ga.W[7] = aWhh + 512;  ga.wstride[7] = 1024;
    ga.klen = 512;
    gemm_mfma<<<dim3(64, 2, 8), 256, 0, stream>>>(ga, 4096, gp);
  }
  lstm_cell<<<128, 256, 0, stream>>>(gp, nullptr, abih, abhh, sc0, h_att, c_att);

  // lbase: sh1@lWhh^T + h_att@lWih[:,2048:]^T, each split in 4 K-quarters
  {
    GemmArgs ga;
#pragma unroll
    for (int q = 0; q < 4; ++q) {
      ga.A[q] = sh1 + q * 256;
      ga.W[q] = lWhh + q * 256;
      ga.wstride[q] = 1024;
      ga.A[4 + q] = h_att + q * 256;
      ga.W[4 + q] = lWih + 2048 + q * 256;
      ga.wstride[4 + q] = 3072;
    }
    ga.klen = 256;
    gemm_mfma<<<dim3(64, 2, 8), 256, 0, stream>>>(ga, 4096, gp);
  }
  reduce8<<<512, 256, 0, stream>>>(gp, lbih, lbhh, lbase);

  for (int i = 0; i < TSTEPS; ++i) {
    attn_fused<<<128, 256, 0, stream>>>(h_att, kvs, vkey, lkey, vval, lval,
                                        vctx, lctx);
    {
      GemmArgs ga;
#pragma unroll
      for (int q = 0; q < 4; ++q) {
        ga.A[q] = vctx + q * 256;
        ga.W[q] = lWih + q * 256;
        ga.wstride[q] = 3072;
        ga.A[4 + q] = lctx + q * 256;
        ga.W[4 + q] = lWih + 1024 + q * 256;
        ga.wstride[4 + q] = 3072;
      }
      ga.klen = 256;
      gemm_mfma<<<dim3(64, 2, 8), 256, 0, stream>>>(ga, 4096, gp);
    }
    lstm_cell<<<128, 256, 0, stream>>>(gp, lbase, nullptr, nullptr, sc1,
                                       h_lang, c_lang);
    {
      GemmArgs ga;
#pragma unroll
      for (int z = 0; z < 8; ++z) {
        ga.A[z] = h_lang + z * 128;
        ga.W[z] = cW1 + z * 128;
        ga.wstride[z] = 1024;
      }
      ga.klen = 128;
      gemm_mfma<<<dim3(16, 2, 8), 256, 0, stream>>>(ga, 1024, gp);
    }
    conf2_halt<<<128, 256, 0, stream>>>(gp, cb1, cW2, cb2, h_lang, c_lang, ws,
                                        (float)(i + 1));
  }

  finalize<<<(int)((O7 / 4 + 255) / 256), 256, 0, stream>>>(ws, vkey, lkey, it,
                                                            (float*)d_out);
}

// Round 6
// 183.678 us; speedup vs baseline: 8.2417x; 1.3505x over previous
//
#include <hip/hip_runtime.h>
#include <hip/hip_bf16.h>

// Sizes (fixed by the reference setup)
constexpr int B  = 128;
constexpr int D  = 1024;
constexpr int NV = 36;
constexpr int NL = 20;
constexpr int BD = B * D;              // 131072
constexpr float EPS = 0.01f;
constexpr int NSLOT = 8;               // split-K slots for the K=4096-class gemms

// Workspace layout (floats). ws is ~268MB; we use ~67MB.
constexpr long SL  = 524288;                     // [128][4096] slot
constexpr long SLB = 2097152;                    // [512][4096] slot
constexpr long OFF_GPA   = 0;                    // 8 slots (att gate partials)
constexpr long OFF_GPLB  = OFF_GPA + 8 * SL;     // 8 slots (lbase partials)
constexpr long OFF_LBASE = OFF_GPLB + 8 * SL;    // [128][4096] (incl. biases)
constexpr long OFF_GPB   = OFF_LBASE + SL;       // 2 slots [512][4096] (loop gates)
constexpr long OFF_GPC   = OFF_GPB + 2 * SLB;    // 2 slots [512][1024] (conf)
constexpr long OFF_HATT  = OFF_GPC + 2 * (SL / 4) * 2; // keep it simple below
// (recompute cleanly:)
constexpr long OFF_GPC0  = OFF_GPB + 2 * SLB;          // conf slot 0 [512][1024]
constexpr long OFF_GPC1  = OFF_GPC0 + 524288;          // conf slot 1
constexpr long OFF_HATT2 = OFF_GPC1 + 524288;          // h_att [128][1024]
constexpr long OFF_CATT2 = OFF_HATT2 + BD;
constexpr long OFF_HLB   = OFF_CATT2 + BD;             // h_lang batched [512][1024]
constexpr long OFF_CLB   = OFF_HLB + 524288;
constexpr long OFF_VCTXB = OFF_CLB + 524288;           // vctx batched [512][1024]
constexpr long OFF_LCTXB = OFF_VCTXB + 524288;
constexpr long OFF_S2    = OFF_LCTXB + 524288;         // S = sum h_lang [128][1024]

typedef float f32x4 __attribute__((ext_vector_type(4)));
typedef short s16x8 __attribute__((ext_vector_type(8)));

__device__ __forceinline__ float sigf(float x) { return 1.f / (1.f + expf(-x)); }

__device__ __forceinline__ short f2bf(float f) {
  __hip_bfloat16 h = __float2bfloat16(f);
  return *reinterpret_cast<short*>(&h);
}

__device__ __forceinline__ f32x4 LD4(const float* p) { return *(const f32x4*)p; }
__device__ __forceinline__ void ST4(float* p, f32x4 v) { *(f32x4*)p = v; }

// ---------------------------------------------------------------------------
// MFMA bf16 GEMM, split-K partials, double-buffered LDS.
// grid (N/64, M/64, KS); block 256 = 4 waves; tile BM=64 BN=64 BK=64.
// partial[z][M][N] = A_z @ W_z^T   (z-chunk pointers pre-offset; A stride 1024)
// ---------------------------------------------------------------------------
struct GemmArgs {
  const float* A[NSLOT];
  const float* W[NSLOT];
  long wstride[NSLOT];
  int klen;                // K per z (multiple of 64)
};

__global__ __launch_bounds__(256, 4) void gemm_mfma(GemmArgs ga, int N,
                                                    long pstride,
                                                    float* __restrict__ gpart) {
  const int z = blockIdx.z;
  const float* __restrict__ A = ga.A[z];
  const float* __restrict__ W = ga.W[z];
  const long wstr = ga.wstride[z];
  const int brow = blockIdx.y * 64;
  const int bcol = blockIdx.x * 64;
  float* __restrict__ out = gpart + (long)z * pstride;

  __shared__ __align__(16) short As[2][64][72];
  __shared__ __align__(16) short Bs[2][64][72];

  const int tid = threadIdx.x;
  const int wave = tid >> 6, lane = tid & 63;
  const int wr = wave >> 1, wc = wave & 1;
  const int lrow = lane & 15;
  const int lk8  = (lane >> 4) * 8;
  const int sr = tid >> 4;
  const int sc4 = (tid & 15) * 4;

  f32x4 acc[2][2];
#pragma unroll
  for (int m = 0; m < 2; ++m)
#pragma unroll
    for (int n = 0; n < 2; ++n) acc[m][n] = (f32x4){0.f, 0.f, 0.f, 0.f};

  float4 ra[4], rw[4];
#define LOAD_TILE(KT)                                                          \
  {                                                                            \
    const int kb = (KT) * 64;                                                  \
    _Pragma("unroll") for (int i = 0; i < 4; ++i) {                            \
      const int r = sr + i * 16;                                               \
      ra[i] = *(const float4*)(A + (long)(brow + r) * 1024 + kb + sc4);        \
      rw[i] = *(const float4*)(W + (long)(bcol + r) * wstr + kb + sc4);        \
    }                                                                          \
  }
#define WRITE_TILE(BUF)                                                        \
  {                                                                            \
    _Pragma("unroll") for (int i = 0; i < 4; ++i) {                            \
      const int r = sr + i * 16;                                               \
      *(short4*)(&As[BUF][r][sc4]) =                                           \
          short4{f2bf(ra[i].x), f2bf(ra[i].y), f2bf(ra[i].z), f2bf(ra[i].w)};  \
      *(short4*)(&Bs[BUF][r][sc4]) =                                           \
          short4{f2bf(rw[i].x), f2bf(rw[i].y), f2bf(rw[i].z), f2bf(rw[i].w)};  \
    }                                                                          \
  }

  const int ntiles = ga.klen / 64;
  LOAD_TILE(0);
  WRITE_TILE(0);
  __syncthreads();
  for (int kt = 0; kt < ntiles; ++kt) {
    const int cur = kt & 1;
    const bool more = (kt + 1 < ntiles);
    if (more) LOAD_TILE(kt + 1);  // in flight during MFMA phase
    s16x8 af[2], bf[2];
#pragma unroll
    for (int kk = 0; kk < 64; kk += 32) {
#pragma unroll
      for (int m = 0; m < 2; ++m)
        af[m] = *(const s16x8*)(&As[cur][wr * 32 + m * 16 + lrow][kk + lk8]);
#pragma unroll
      for (int n = 0; n < 2; ++n)
        bf[n] = *(const s16x8*)(&Bs[cur][wc * 32 + n * 16 + lrow][kk + lk8]);
#pragma unroll
      for (int m = 0; m < 2; ++m)
#pragma unroll
        for (int n = 0; n < 2; ++n)
          acc[m][n] = __builtin_amdgcn_mfma_f32_16x16x32_bf16(
              af[m], bf[n], acc[m][n], 0, 0, 0);
    }
    if (more) WRITE_TILE(1 - cur);
    __syncthreads();
  }
#undef LOAD_TILE
#undef WRITE_TILE

#pragma unroll
  for (int m = 0; m < 2; ++m) {
#pragma unroll
    for (int n = 0; n < 2; ++n) {
      const int col = bcol + wc * 32 + n * 16 + lrow;
#pragma unroll
      for (int r = 0; r < 4; ++r) {
        const int row = brow + wr * 32 + m * 16 + (lane >> 4) * 4 + r;
        out[(long)row * N + col] = acc[m][n][r];
      }
    }
  }
}

// ---------------------------------------------------------------------------
// att LSTM cell: gates = sum of 8 partials + bih + bhh -> h_att, c_att
// ---------------------------------------------------------------------------
__global__ __launch_bounds__(256) void lstm_att(
    const float* __restrict__ gp, const float* __restrict__ bih,
    const float* __restrict__ bhh, const float* __restrict__ c_prev,
    float* __restrict__ h, float* __restrict__ c) {
  long idx = ((long)blockIdx.x * 256 + threadIdx.x) * 4;
  if (idx >= BD) return;
  int b = (int)(idx >> 10), d = (int)(idx & 1023);
  const long base = (long)b * 4096 + d;
  f32x4 g[4];
#pragma unroll
  for (int gi = 0; gi < 4; ++gi) {
    const long o = base + gi * 1024;
    f32x4 v = LD4(bih + gi * 1024 + d) + LD4(bhh + gi * 1024 + d);
#pragma unroll
    for (int s = 0; s < NSLOT; ++s) v += LD4(gp + s * SL + o);
    g[gi] = v;
  }
  f32x4 cp = LD4(c_prev + idx), cc, hh;
#pragma unroll
  for (int j = 0; j < 4; ++j) {
    float ccj = sigf(g[1][j]) * cp[j] + sigf(g[0][j]) * tanhf(g[2][j]);
    cc[j] = ccj;
    hh[j] = sigf(g[3][j]) * tanhf(ccj);
  }
  ST4(c + idx, cc);
  ST4(h + idx, hh);
}

// ---------------------------------------------------------------------------
// reduce8: lbase = sum of 8 partials + bih + bhh
// ---------------------------------------------------------------------------
__global__ __launch_bounds__(256) void reduce8(
    const float* __restrict__ gp, const float* __restrict__ bih,
    const float* __restrict__ bhh, float* __restrict__ out) {
  long idx = ((long)blockIdx.x * 256 + threadIdx.x) * 4;
  if (idx >= (long)B * 4096) return;
  int col = (int)(idx & 4095);
  f32x4 v = LD4(bih + col) + LD4(bhh + col);
#pragma unroll
  for (int s = 0; s < NSLOT; ++s) v += LD4(gp + s * SL + idx);
  ST4(out + idx, v);
}

// ---------------------------------------------------------------------------
// attn_mega: all 4 attention steps for one batch element. kvs recurrence is
// internal (registers); softmax over ORIGINAL keys (the in-loop key update is
// slot-uniform and cancels in softmax). Writes vctxB/lctxB [step*128+b][1024]
// and the final kvs straight into the d_out kvs section.
// ---------------------------------------------------------------------------
__global__ __launch_bounds__(256) void attn_mega(
    const float* __restrict__ h_att, const float* __restrict__ kv0,
    const float* __restrict__ vkey, const float* __restrict__ lkey,
    const float* __restrict__ vval, const float* __restrict__ lval,
    float* __restrict__ vctxB, float* __restrict__ lctxB,
    float* __restrict__ out_kvs) {
  const int b = blockIdx.x, tid = threadIdx.x;
  const int d0 = tid * 4;
  __shared__ float q[1024];
  __shared__ float wgt[64];
  const f32x4 ha = LD4(h_att + (long)b * 1024 + d0);
  f32x4 kv = LD4(kv0 + (long)b * 1024 + d0);
  const int wave = tid >> 6, lane = tid & 63;

  for (int step = 0; step < 4; ++step) {
    ST4(q + d0, ha + kv);
    __syncthreads();
    // logits (scaled by 1/sqrt(1024))
    for (int n = wave; n < NV + NL; n += 4) {
      const float* key = (n < NV) ? (vkey + ((long)b * NV + n) * 1024)
                                  : (lkey + ((long)b * NL + (n - NV)) * 1024);
      float s = 0.f;
#pragma unroll
      for (int j = 0; j < 4; ++j) {
        f32x4 k4 = LD4(key + lane * 4 + j * 256);
        f32x4 q4 = *(const f32x4*)(&q[lane * 4 + j * 256]);
        s += k4[0] * q4[0] + k4[1] * q4[1] + k4[2] * q4[2] + k4[3] * q4[3];
      }
      for (int m = 32; m >= 1; m >>= 1) s += __shfl_xor(s, m);
      if (lane == 0) wgt[n] = s * (1.0f / 32.0f);
    }
    __syncthreads();
    // softmax (wave0: visual, wave1: language)
    if (wave == 0) {
      float x = (lane < NV) ? wgt[lane] : -1e30f;
      float m = x;
      for (int k = 32; k >= 1; k >>= 1) m = fmaxf(m, __shfl_xor(m, k));
      float e = (lane < NV) ? expf(x - m) : 0.f;
      float ssum = e;
      for (int k = 32; k >= 1; k >>= 1) ssum += __shfl_xor(ssum, k);
      if (lane < NV) wgt[lane] = e / ssum;
    } else if (wave == 1) {
      float x = (lane < NL) ? wgt[NV + lane] : -1e30f;
      float m = x;
      for (int k = 32; k >= 1; k >>= 1) m = fmaxf(m, __shfl_xor(m, k));
      float e = (lane < NL) ? expf(x - m) : 0.f;
      float ssum = e;
      for (int k = 32; k >= 1; k >>= 1) ssum += __shfl_xor(ssum, k);
      if (lane < NL) wgt[NV + lane] = e / ssum;
    }
    __syncthreads();
    // context + kvs update
    f32x4 vc = (f32x4){0.f, 0.f, 0.f, 0.f}, lc = vc;
    const float* vp = vval + (long)b * NV * 1024 + d0;
#pragma unroll 6
    for (int n = 0; n < NV; ++n) vc += LD4(vp + (long)n * 1024) * wgt[n];
    const float* lp = lval + (long)b * NL * 1024 + d0;
#pragma unroll 5
    for (int n = 0; n < NL; ++n) lc += LD4(lp + (long)n * 1024) * wgt[NV + n];
    const long orow = ((long)step * 128 + b) * 1024 + d0;
    ST4(vctxB + orow, vc);
    ST4(lctxB + orow, lc);
    kv = kv + vc + lc;
#pragma unroll
    for (int j = 0; j < 4; ++j) kv[j] = tanhf(kv[j]);
    __syncthreads();  // protect q/wgt for next step
  }
  ST4(out_kvs + (long)b * 1024 + d0, kv);
}

// ---------------------------------------------------------------------------
// batched lang LSTM (M=512 = 4 steps x 128): gates = gpB0+gpB1 + lbase[b]
// (lbase already includes both biases); c_prev = sc1[b] (state is NOT updated
// across halting steps in the reference).
// ---------------------------------------------------------------------------
__global__ __launch_bounds__(256) void lstm_batch(
    const float* __restrict__ gpB, const float* __restrict__ lbase,
    const float* __restrict__ sc1, float* __restrict__ hB,
    float* __restrict__ cB) {
  long idx = ((long)blockIdx.x * 256 + threadIdx.x) * 4;
  if (idx >= 512L * 1024) return;
  const int row = (int)(idx >> 10);   // 0..511 (step*128+b)
  const int b = row & 127;
  const int d = (int)(idx & 1023);
  const long base = (long)row * 4096 + d;
  const long lbbase = (long)b * 4096 + d;
  f32x4 g[4];
#pragma unroll
  for (int gi = 0; gi < 4; ++gi) {
    const long o = gi * 1024;
    g[gi] = LD4(gpB + base + o) + LD4(gpB + SLB + base + o) +
            LD4(lbase + lbbase + o);
  }
  f32x4 cp = LD4(sc1 + (long)b * 1024 + d), cc, hh;
#pragma unroll
  for (int j = 0; j < 4; ++j) {
    float ccj = sigf(g[1][j]) * cp[j] + sigf(g[0][j]) * tanhf(g[2][j]);
    cc[j] = ccj;
    hh[j] = sigf(g[3][j]) * tanhf(ccj);
  }
  ST4(cB + idx, cc);
  ST4(hB + idx, hh);
}

// ---------------------------------------------------------------------------
// halt_scan: per batch element, compute p_i for the 4 steps from the conf
// partials, run the halting recurrence in registers, and write outA /
// new_h[1] / new_c[1] / cost directly into d_out. Also writes S = sum h_lang.
// ---------------------------------------------------------------------------
constexpr long O1 = BD;
constexpr long O2 = O1 + (long)B * NV * D;
constexpr long O3 = O2 + (long)B * NL * D;
constexpr long O4 = O3 + B;
constexpr long O5 = O4 + 2L * BD;
constexpr long O6 = O5 + 2L * BD;
constexpr long O7 = O6 + BD;

__global__ __launch_bounds__(256) void halt_scan(
    const float* __restrict__ gpc0, const float* __restrict__ gpc1,
    const float* __restrict__ cb1, const float* __restrict__ W2,
    const float* __restrict__ b2, const float* __restrict__ hB,
    const float* __restrict__ cB, const int* __restrict__ it,
    float* __restrict__ Sout, float* __restrict__ out) {
  const int b = blockIdx.x, tid = threadIdx.x;
  const int d0 = tid * 4;
  __shared__ float red[256];
  __shared__ float p_sh;
  const f32x4 w4 = LD4(W2 + d0);
  const f32x4 cb = LD4(cb1 + d0);
  f32x4 hl_acc = (f32x4){0.f, 0.f, 0.f, 0.f}, cl_acc = hl_acc, s_acc = hl_acc;
  float a = 0.f, sel = 1.f, cost = 0.f;

  for (int i = 0; i < 4; ++i) {
    const long row = (long)i * 128 + b;
    const long o = row * 1024 + d0;
    f32x4 rv = LD4(gpc0 + o) + LD4(gpc1 + o) + cb;
    float part = 0.f;
#pragma unroll
    for (int j = 0; j < 4; ++j) part += fmaxf(rv[j], 0.f) * w4[j];
    red[tid] = part;
    __syncthreads();
    for (int s = 128; s > 0; s >>= 1) {
      if (tid < s) red[tid] += red[tid + s];
      __syncthreads();
    }
    if (tid == 0) p_sh = sigf(red[0] + b2[0]);
    __syncthreads();
    const float p = p_sh;
    const float bs = p * (1.f - a) * sel;
    f32x4 hl = LD4(hB + o), cl = LD4(cB + o);
    hl_acc += hl * bs;
    cl_acc += cl * bs;
    s_acc += hl;                        // key update is unmasked in reference
    cost += (float)(i + 1) * (1.f - p) * sel;
    a += bs;
    sel = (a < 1.f - EPS) ? sel : 0.f;
    __syncthreads();                    // p_sh reuse
  }
  const float inv_a = 1.f / a;
  const long ob = (long)b * 1024 + d0;
  ST4(out + ob, hl_acc * inv_a);             // outA
  ST4(out + O4 + BD + ob, hl_acc * inv_a);   // new_h[1]
  ST4(out + O5 + BD + ob, cl_acc * inv_a);   // new_c[1]
  ST4(Sout + ob, s_acc);
  if (tid == 0) out[O3 + b] = cost * ((it[b] > 0) ? 1.f : 0.f);
}

// ---------------------------------------------------------------------------
// finalize2: vkey/lkey outputs (+0.01*S broadcast) and new_h[0]/new_c[0]
// (= h_att / c_att exactly, since hA/accum == h_att). kvs written by attn_mega.
// ---------------------------------------------------------------------------
constexpr long VK = (long)B * NV * D;     // 4,718,592
constexpr long LK = (long)B * NL * D;     // 2,621,440

__global__ __launch_bounds__(256) void finalize2(
    const float* __restrict__ vkey0, const float* __restrict__ lkey0,
    const float* __restrict__ S, const float* __restrict__ h_att,
    const float* __restrict__ c_att, float* __restrict__ out) {
  long idx = ((long)blockIdx.x * 256 + threadIdx.x) * 4;
  if (idx < VK) {
    int b = (int)(idx / (NV * 1024));
    int d = (int)(idx & 1023);
    ST4(out + O1 + idx, LD4(vkey0 + idx) + LD4(S + (long)b * 1024 + d) * 0.01f);
  } else if (idx < VK + LK) {
    long r = idx - VK;
    int b = (int)(r / (NL * 1024));
    int d = (int)(r & 1023);
    ST4(out + O2 + r, LD4(lkey0 + r) + LD4(S + (long)b * 1024 + d) * 0.01f);
  } else if (idx < VK + LK + BD) {
    long r = idx - VK - LK;
    ST4(out + O4 + r, LD4(h_att + r));    // new_h[0]
  } else if (idx < VK + LK + 2L * BD) {
    long r = idx - VK - LK - BD;
    ST4(out + O5 + r, LD4(c_att + r));    // new_c[0]
  }
}

// ---------------------------------------------------------------------------
extern "C" void kernel_launch(void* const* d_in, const int* in_sizes, int n_in,
                              void* d_out, int out_size, void* d_ws, size_t ws_size,
                              hipStream_t stream) {
  const float* xt   = (const float*)d_in[0];
  const int*   it   = (const int*)d_in[1];
  const float* fc   = (const float*)d_in[2];
  const float* vval = (const float*)d_in[3];
  const float* vkey = (const float*)d_in[4];
  const float* lval = (const float*)d_in[5];
  const float* lkey = (const float*)d_in[6];
  const float* kv0  = (const float*)d_in[7];
  const float* sh   = (const float*)d_in[8];   // [2,B,D]
  const float* sc   = (const float*)d_in[9];   // [2,B,D]
  // d_in[10] = max_att_step (4)
  const float* aWih = (const float*)d_in[11];  // [4096,3072]
  const float* aWhh = (const float*)d_in[12];  // [4096,1024]
  const float* abih = (const float*)d_in[13];
  const float* abhh = (const float*)d_in[14];
  const float* lWih = (const float*)d_in[15];  // [4096,3072]
  const float* lWhh = (const float*)d_in[16];  // [4096,1024]
  const float* lbih = (const float*)d_in[17];
  const float* lbhh = (const float*)d_in[18];
  const float* cW1  = (const float*)d_in[19];  // [1024,1024]
  const float* cb1  = (const float*)d_in[20];
  const float* cW2  = (const float*)d_in[21];  // [1,1024]
  const float* cb2  = (const float*)d_in[22];

  float* ws = (float*)d_ws;
  float* gpA   = ws + OFF_GPA;
  float* gpLB  = ws + OFF_GPLB;
  float* lbase = ws + OFF_LBASE;
  float* gpB   = ws + OFF_GPB;
  float* gpC0  = ws + OFF_GPC0;
  float* gpC1  = ws + OFF_GPC1;
  float* h_att = ws + OFF_HATT2;
  float* c_att = ws + OFF_CATT2;
  float* hB    = ws + OFF_HLB;
  float* cB    = ws + OFF_CLB;
  float* vctxB = ws + OFF_VCTXB;
  float* lctxB = ws + OFF_LCTXB;
  float* Sbuf  = ws + OFF_S2;

  const float* sh1 = sh + BD;  // state_h[1]
  const float* sc0 = sc;       // state_c[0]
  const float* sc1 = sc + BD;  // state_c[1]
  float* out = (float*)d_out;

  // 1) att gates: [sh1,fc,xt]@aWih^T + sh0@aWhh^T, K pairs split in 2
  {
    GemmArgs ga;
    ga.A[0] = sh1;       ga.W[0] = aWih;        ga.wstride[0] = 3072;
    ga.A[1] = sh1 + 512; ga.W[1] = aWih + 512;  ga.wstride[1] = 3072;
    ga.A[2] = fc;        ga.W[2] = aWih + 1024; ga.wstride[2] = 3072;
    ga.A[3] = fc + 512;  ga.W[3] = aWih + 1536; ga.wstride[3] = 3072;
    ga.A[4] = xt;        ga.W[4] = aWih + 2048; ga.wstride[4] = 3072;
    ga.A[5] = xt + 512;  ga.W[5] = aWih + 2560; ga.wstride[5] = 3072;
    ga.A[6] = sh;        ga.W[6] = aWhh;        ga.wstride[6] = 1024;
    ga.A[7] = sh + 512;  ga.W[7] = aWhh + 512;  ga.wstride[7] = 1024;
    ga.klen = 512;
    gemm_mfma<<<dim3(64, 2, 8), 256, 0, stream>>>(ga, 4096, SL, gpA);
  }
  // 2) att LSTM -> h_att, c_att
  lstm_att<<<128, 256, 0, stream>>>(gpA, abih, abhh, sc0, h_att, c_att);

  // 3) lbase partials: sh1@lWhh^T + h_att@lWih[:,2048:]^T (K quarters)
  {
    GemmArgs ga;
#pragma unroll
    for (int q = 0; q < 4; ++q) {
      ga.A[q] = sh1 + q * 256;
      ga.W[q] = lWhh + q * 256;
      ga.wstride[q] = 1024;
      ga.A[4 + q] = h_att + q * 256;
      ga.W[4 + q] = lWih + 2048 + q * 256;
      ga.wstride[4 + q] = 3072;
    }
    ga.klen = 256;
    gemm_mfma<<<dim3(64, 2, 8), 256, 0, stream>>>(ga, 4096, SL, gpLB);
  }
  // 4) lbase reduce (+ both biases)
  reduce8<<<512, 256, 0, stream>>>(gpLB, lbih, lbhh, lbase);

  // 5) all 4 attention steps (kvs recurrence internal); writes out kvs section
  attn_mega<<<128, 256, 0, stream>>>(h_att, kv0, vkey, lkey, vval, lval,
                                     vctxB, lctxB, out + O6);

  // 6) batched loop gates: M=512; weights read once.
  {
    GemmArgs ga;
    ga.A[0] = vctxB; ga.W[0] = lWih;        ga.wstride[0] = 3072;
    ga.A[1] = lctxB; ga.W[1] = lWih + 1024; ga.wstride[1] = 3072;
#pragma unroll
    for (int z = 2; z < 8; ++z) { ga.A[z] = vctxB; ga.W[z] = lWih; ga.wstride[z] = 3072; }
    ga.klen = 1024;
    gemm_mfma<<<dim3(64, 8, 2), 256, 0, stream>>>(ga, 4096, SLB, gpB);
  }
  // 7) batched lang LSTM
  lstm_batch<<<512, 256, 0, stream>>>(gpB, lbase, sc1, hB, cB);

  // 8) batched conf GEMM: M=512, N=1024, K=1024 split in 2
  {
    GemmArgs ga;
    ga.A[0] = hB;       ga.W[0] = cW1;       ga.wstride[0] = 1024;
    ga.A[1] = hB + 512; ga.W[1] = cW1 + 512; ga.wstride[1] = 1024;
#pragma unroll
    for (int z = 2; z < 8; ++z) { ga.A[z] = hB; ga.W[z] = cW1; ga.wstride[z] = 1024; }
    ga.klen = 512;
    gemm_mfma<<<dim3(16, 8, 2), 256, 0, stream>>>(ga, 1024, 524288, gpC0);
  }
  // 9) halting scan -> outA, new_h[1], new_c[1], cost, S
  halt_scan<<<128, 256, 0, stream>>>(gpC0, gpC1, cb1, cW2, cb2, hB, cB, it,
                                     Sbuf, out);
  // 10) key outputs + new_h[0]/new_c[0]
  finalize2<<<7424, 256, 0, stream>>>(vkey, lkey, Sbuf, h_att, c_att, out);
}

// Round 7
// 150.778 us; speedup vs baseline: 10.0400x; 1.2182x over previous
//
#include <hip/hip_runtime.h>
#include <hip/hip_bf16.h>

// Sizes (fixed by the reference setup)
constexpr int B  = 128;
constexpr int D  = 1024;
constexpr int NV = 36;
constexpr int NL = 20;
constexpr int BD = B * D;              // 131072
constexpr float EPS = 0.01f;
constexpr int NSLOT = 8;

// Workspace layout (floats)
constexpr long SL  = 524288;                     // [128][4096] slot
constexpr long SLB = 2097152;                    // [512][4096] slot
constexpr long OFF_GPA   = 0;                    // 8 slots (att gate partials)
constexpr long OFF_GPLB  = OFF_GPA + 8 * SL;     // 8 slots (lbase partials)
constexpr long OFF_LBASE = OFF_GPLB + 8 * SL;    // [128][4096] (incl. biases)
constexpr long OFF_GPB   = OFF_LBASE + SL;       // 2 slots [512][4096] (loop gates)
constexpr long OFF_GPC0  = OFF_GPB + 2 * SLB;    // conf slot 0 [512][1024]
constexpr long OFF_GPC1  = OFF_GPC0 + 524288;    // conf slot 1
constexpr long OFF_HATT2 = OFF_GPC1 + 524288;    // h_att [128][1024]
constexpr long OFF_CATT2 = OFF_HATT2 + BD;
constexpr long OFF_HLB   = OFF_CATT2 + BD;       // h_lang batched [512][1024]
constexpr long OFF_CLB   = OFF_HLB + 524288;
constexpr long OFF_VCTXB = OFF_CLB + 524288;     // vctx batched [512][1024]
constexpr long OFF_LCTXB = OFF_VCTXB + 524288;
constexpr long OFF_S2    = OFF_LCTXB + 524288;   // S = sum h_lang [128][1024]

typedef float f32x4 __attribute__((ext_vector_type(4)));
typedef short s16x8 __attribute__((ext_vector_type(8)));

__device__ __forceinline__ float sigf(float x) { return 1.f / (1.f + expf(-x)); }

__device__ __forceinline__ short f2bf(float f) {
  __hip_bfloat16 h = __float2bfloat16(f);
  return *reinterpret_cast<short*>(&h);
}

__device__ __forceinline__ f32x4 LD4(const float* p) { return *(const f32x4*)p; }
__device__ __forceinline__ void ST4(float* p, f32x4 v) { *(f32x4*)p = v; }

// ---------------------------------------------------------------------------
// MFMA bf16 GEMM, split-K partials, double-buffered LDS, tile BM=128 BN=64
// BK=64 (W-operand re-read multiplicity = M/128). grid (N/64, M/128, KS);
// block 256 = 4 waves (2x2), each wave 64x32 out.
// partial[z][M][N] = A_z @ W_z^T   (z pointers pre-offset; A stride 1024)
// ---------------------------------------------------------------------------
struct GemmArgs {
  const float* A[NSLOT];
  const float* W[NSLOT];
  long wstride[NSLOT];
  int klen;                // K per z (multiple of 64)
};

__global__ __launch_bounds__(256, 2) void gemm_mfma(GemmArgs ga, int N,
                                                    long pstride,
                                                    float* __restrict__ gpart) {
  const int z = blockIdx.z;
  const float* __restrict__ A = ga.A[z];
  const float* __restrict__ W = ga.W[z];
  const long wstr = ga.wstride[z];
  const int brow = blockIdx.y * 128;
  const int bcol = blockIdx.x * 64;
  float* __restrict__ out = gpart + (long)z * pstride;

  __shared__ __align__(16) short As[2][128][72];
  __shared__ __align__(16) short Bs[2][64][72];

  const int tid = threadIdx.x;
  const int wave = tid >> 6, lane = tid & 63;
  const int wr = wave >> 1, wc = wave & 1;
  const int lrow = lane & 15;
  const int lk8  = (lane >> 4) * 8;
  const int sr = tid >> 4;          // 0..15
  const int sc4 = (tid & 15) * 4;   // 0..60

  f32x4 acc[4][2];
#pragma unroll
  for (int m = 0; m < 4; ++m)
#pragma unroll
    for (int n = 0; n < 2; ++n) acc[m][n] = (f32x4){0.f, 0.f, 0.f, 0.f};

  float4 ra[8], rw[4];
#define LOAD_TILE(KT)                                                          \
  {                                                                            \
    const int kb = (KT) * 64;                                                  \
    _Pragma("unroll") for (int i = 0; i < 8; ++i) {                            \
      const int r = sr + i * 16;                                               \
      ra[i] = *(const float4*)(A + (long)(brow + r) * 1024 + kb + sc4);        \
    }                                                                          \
    _Pragma("unroll") for (int i = 0; i < 4; ++i) {                            \
      const int r = sr + i * 16;                                               \
      rw[i] = *(const float4*)(W + (long)(bcol + r) * wstr + kb + sc4);        \
    }                                                                          \
  }
#define WRITE_TILE(BUF)                                                        \
  {                                                                            \
    _Pragma("unroll") for (int i = 0; i < 8; ++i) {                            \
      const int r = sr + i * 16;                                               \
      *(short4*)(&As[BUF][r][sc4]) =                                           \
          short4{f2bf(ra[i].x), f2bf(ra[i].y), f2bf(ra[i].z), f2bf(ra[i].w)};  \
    }                                                                          \
    _Pragma("unroll") for (int i = 0; i < 4; ++i) {                            \
      const int r = sr + i * 16;                                               \
      *(short4*)(&Bs[BUF][r][sc4]) =                                           \
          short4{f2bf(rw[i].x), f2bf(rw[i].y), f2bf(rw[i].z), f2bf(rw[i].w)};  \
    }                                                                          \
  }

  const int ntiles = ga.klen / 64;
  LOAD_TILE(0);
  WRITE_TILE(0);
  __syncthreads();
  for (int kt = 0; kt < ntiles; ++kt) {
    const int cur = kt & 1;
    const bool more = (kt + 1 < ntiles);
    if (more) LOAD_TILE(kt + 1);  // in flight during MFMA phase
#pragma unroll
    for (int kk = 0; kk < 64; kk += 32) {
      s16x8 af[4], bf[2];
#pragma unroll
      for (int m = 0; m < 4; ++m)
        af[m] = *(const s16x8*)(&As[cur][wr * 64 + m * 16 + lrow][kk + lk8]);
#pragma unroll
      for (int n = 0; n < 2; ++n)
        bf[n] = *(const s16x8*)(&Bs[cur][wc * 32 + n * 16 + lrow][kk + lk8]);
#pragma unroll
      for (int m = 0; m < 4; ++m)
#pragma unroll
        for (int n = 0; n < 2; ++n)
          acc[m][n] = __builtin_amdgcn_mfma_f32_16x16x32_bf16(
              af[m], bf[n], acc[m][n], 0, 0, 0);
    }
    if (more) WRITE_TILE(1 - cur);
    __syncthreads();
  }
#undef LOAD_TILE
#undef WRITE_TILE

  // C/D layout: col=lane&15, row=(lane>>4)*4+reg
#pragma unroll
  for (int m = 0; m < 4; ++m) {
#pragma unroll
    for (int n = 0; n < 2; ++n) {
      const int col = bcol + wc * 32 + n * 16 + lrow;
#pragma unroll
      for (int r = 0; r < 4; ++r) {
        const int row = brow + wr * 64 + m * 16 + (lane >> 4) * 4 + r;
        out[(long)row * N + col] = acc[m][n][r];
      }
    }
  }
}

// ---------------------------------------------------------------------------
// att LSTM cell: gates = sum of 8 partials + bih + bhh -> h_att, c_att
// ---------------------------------------------------------------------------
__global__ __launch_bounds__(256) void lstm_att(
    const float* __restrict__ gp, const float* __restrict__ bih,
    const float* __restrict__ bhh, const float* __restrict__ c_prev,
    float* __restrict__ h, float* __restrict__ c) {
  long idx = ((long)blockIdx.x * 256 + threadIdx.x) * 4;
  if (idx >= BD) return;
  int b = (int)(idx >> 10), d = (int)(idx & 1023);
  const long base = (long)b * 4096 + d;
  f32x4 g[4];
#pragma unroll
  for (int gi = 0; gi < 4; ++gi) {
    const long o = base + gi * 1024;
    f32x4 v = LD4(bih + gi * 1024 + d) + LD4(bhh + gi * 1024 + d);
#pragma unroll
    for (int s = 0; s < NSLOT; ++s) v += LD4(gp + s * SL + o);
    g[gi] = v;
  }
  f32x4 cp = LD4(c_prev + idx), cc, hh;
#pragma unroll
  for (int j = 0; j < 4; ++j) {
    float ccj = sigf(g[1][j]) * cp[j] + sigf(g[0][j]) * tanhf(g[2][j]);
    cc[j] = ccj;
    hh[j] = sigf(g[3][j]) * tanhf(ccj);
  }
  ST4(c + idx, cc);
  ST4(h + idx, hh);
}

// ---------------------------------------------------------------------------
// reduce8: lbase = sum of 8 partials + bih + bhh
// ---------------------------------------------------------------------------
__global__ __launch_bounds__(256) void reduce8(
    const float* __restrict__ gp, const float* __restrict__ bih,
    const float* __restrict__ bhh, float* __restrict__ out) {
  long idx = ((long)blockIdx.x * 256 + threadIdx.x) * 4;
  if (idx >= (long)B * 4096) return;
  int col = (int)(idx & 4095);
  f32x4 v = LD4(bih + col) + LD4(bhh + col);
#pragma unroll
  for (int s = 0; s < NSLOT; ++s) v += LD4(gp + s * SL + idx);
  ST4(out + idx, v);
}

// ---------------------------------------------------------------------------
// attn_mega: all 4 attention steps for one batch element, 1024 threads
// (16 waves) per block for latency hiding. kvs recurrence in registers;
// softmax over ORIGINAL keys (slot-uniform update cancels in softmax).
// Writes vctxB/lctxB [step*128+b][1024] and final kvs into d_out kvs section.
// ---------------------------------------------------------------------------
__global__ __launch_bounds__(1024) void attn_mega(
    const float* __restrict__ h_att, const float* __restrict__ kv0,
    const float* __restrict__ vkey, const float* __restrict__ lkey,
    const float* __restrict__ vval, const float* __restrict__ lval,
    float* __restrict__ vctxB, float* __restrict__ lctxB,
    float* __restrict__ out_kvs) {
  const int b = blockIdx.x, tid = threadIdx.x;   // tid = d column
  __shared__ float q[1024];
  __shared__ float wgt[64];
  const float ha = h_att[(long)b * 1024 + tid];
  float kv = kv0[(long)b * 1024 + tid];
  const int wave = tid >> 6, lane = tid & 63;

  for (int step = 0; step < 4; ++step) {
    q[tid] = ha + kv;
    __syncthreads();
    // logits: 56 keys over 16 waves (3-4 each); coalesced f32x4 lane reads
    for (int n = wave; n < NV + NL; n += 16) {
      const float* key = (n < NV) ? (vkey + ((long)b * NV + n) * 1024)
                                  : (lkey + ((long)b * NL + (n - NV)) * 1024);
      float s = 0.f;
#pragma unroll
      for (int j = 0; j < 4; ++j) {
        f32x4 k4 = LD4(key + lane * 4 + j * 256);
        f32x4 q4 = *(const f32x4*)(&q[lane * 4 + j * 256]);
        s += k4[0] * q4[0] + k4[1] * q4[1] + k4[2] * q4[2] + k4[3] * q4[3];
      }
      for (int m = 32; m >= 1; m >>= 1) s += __shfl_xor(s, m);
      if (lane == 0) wgt[n] = s * (1.0f / 32.0f);
    }
    __syncthreads();
    // softmax (wave0: visual, wave1: language)
    if (wave == 0) {
      float x = (lane < NV) ? wgt[lane] : -1e30f;
      float m = x;
      for (int k = 32; k >= 1; k >>= 1) m = fmaxf(m, __shfl_xor(m, k));
      float e = (lane < NV) ? expf(x - m) : 0.f;
      float ssum = e;
      for (int k = 32; k >= 1; k >>= 1) ssum += __shfl_xor(ssum, k);
      if (lane < NV) wgt[lane] = e / ssum;
    } else if (wave == 1) {
      float x = (lane < NL) ? wgt[NV + lane] : -1e30f;
      float m = x;
      for (int k = 32; k >= 1; k >>= 1) m = fmaxf(m, __shfl_xor(m, k));
      float e = (lane < NL) ? expf(x - m) : 0.f;
      float ssum = e;
      for (int k = 32; k >= 1; k >>= 1) ssum += __shfl_xor(ssum, k);
      if (lane < NL) wgt[NV + lane] = e / ssum;
    }
    __syncthreads();
    // context + kvs update: 1 col/thread, coalesced scalar loads
    float vc = 0.f, lc = 0.f;
    const float* vp = vval + (long)b * NV * 1024 + tid;
#pragma unroll 6
    for (int n = 0; n < NV; ++n) vc += vp[(long)n * 1024] * wgt[n];
    const float* lp = lval + (long)b * NL * 1024 + tid;
#pragma unroll 5
    for (int n = 0; n < NL; ++n) lc += lp[(long)n * 1024] * wgt[NV + n];
    const long orow = ((long)step * 128 + b) * 1024 + tid;
    vctxB[orow] = vc;
    lctxB[orow] = lc;
    kv = tanhf(kv + vc + lc);
    __syncthreads();  // protect q/wgt for next step
  }
  out_kvs[(long)b * 1024 + tid] = kv;
}

// ---------------------------------------------------------------------------
// batched lang LSTM (M=512 = 4 steps x 128): gates = gpB0+gpB1 + lbase[b]
// (lbase includes both biases); c_prev = sc1[b] (state constant across steps).
// ---------------------------------------------------------------------------
__global__ __launch_bounds__(256) void lstm_batch(
    const float* __restrict__ gpB, const float* __restrict__ lbase,
    const float* __restrict__ sc1, float* __restrict__ hB,
    float* __restrict__ cB) {
  long idx = ((long)blockIdx.x * 256 + threadIdx.x) * 4;
  if (idx >= 512L * 1024) return;
  const int row = (int)(idx >> 10);   // step*128+b
  const int b = row & 127;
  const int d = (int)(idx & 1023);
  const long base = (long)row * 4096 + d;
  const long lbbase = (long)b * 4096 + d;
  f32x4 g[4];
#pragma unroll
  for (int gi = 0; gi < 4; ++gi) {
    const long o = gi * 1024;
    g[gi] = LD4(gpB + base + o) + LD4(gpB + SLB + base + o) +
            LD4(lbase + lbbase + o);
  }
  f32x4 cp = LD4(sc1 + (long)b * 1024 + d), cc, hh;
#pragma unroll
  for (int j = 0; j < 4; ++j) {
    float ccj = sigf(g[1][j]) * cp[j] + sigf(g[0][j]) * tanhf(g[2][j]);
    cc[j] = ccj;
    hh[j] = sigf(g[3][j]) * tanhf(ccj);
  }
  ST4(cB + idx, cc);
  ST4(hB + idx, hh);
}

// ---------------------------------------------------------------------------
// halt_scan: per-b halting recurrence over 4 steps; writes outA / new_h[1] /
// new_c[1] / cost into d_out and S = sum h_lang.
// ---------------------------------------------------------------------------
constexpr long O1 = BD;
constexpr long O2 = O1 + (long)B * NV * D;
constexpr long O3 = O2 + (long)B * NL * D;
constexpr long O4 = O3 + B;
constexpr long O5 = O4 + 2L * BD;
constexpr long O6 = O5 + 2L * BD;
constexpr long O7 = O6 + BD;

__global__ __launch_bounds__(256) void halt_scan(
    const float* __restrict__ gpc0, const float* __restrict__ gpc1,
    const float* __restrict__ cb1, const float* __restrict__ W2,
    const float* __restrict__ b2, const float* __restrict__ hB,
    const float* __restrict__ cB, const int* __restrict__ it,
    float* __restrict__ Sout, float* __restrict__ out) {
  const int b = blockIdx.x, tid = threadIdx.x;
  const int d0 = tid * 4;
  __shared__ float red[256];
  __shared__ float p_sh;
  const f32x4 w4 = LD4(W2 + d0);
  const f32x4 cb = LD4(cb1 + d0);
  f32x4 hl_acc = (f32x4){0.f, 0.f, 0.f, 0.f}, cl_acc = hl_acc, s_acc = hl_acc;
  float a = 0.f, sel = 1.f, cost = 0.f;

  for (int i = 0; i < 4; ++i) {
    const long o = ((long)i * 128 + b) * 1024 + d0;
    f32x4 rv = LD4(gpc0 + o) + LD4(gpc1 + o) + cb;
    float part = 0.f;
#pragma unroll
    for (int j = 0; j < 4; ++j) part += fmaxf(rv[j], 0.f) * w4[j];
    red[tid] = part;
    __syncthreads();
    for (int s = 128; s > 0; s >>= 1) {
      if (tid < s) red[tid] += red[tid + s];
      __syncthreads();
    }
    if (tid == 0) p_sh = sigf(red[0] + b2[0]);
    __syncthreads();
    const float p = p_sh;
    const float bs = p * (1.f - a) * sel;
    f32x4 hl = LD4(hB + o), cl = LD4(cB + o);
    hl_acc += hl * bs;
    cl_acc += cl * bs;
    s_acc += hl;                        // key update unmasked in reference
    cost += (float)(i + 1) * (1.f - p) * sel;
    a += bs;
    sel = (a < 1.f - EPS) ? sel : 0.f;
    __syncthreads();                    // p_sh reuse
  }
  const float inv_a = 1.f / a;
  const long ob = (long)b * 1024 + d0;
  ST4(out + ob, hl_acc * inv_a);             // outA
  ST4(out + O4 + BD + ob, hl_acc * inv_a);   // new_h[1]
  ST4(out + O5 + BD + ob, cl_acc * inv_a);   // new_c[1]
  ST4(Sout + ob, s_acc);
  if (tid == 0) out[O3 + b] = cost * ((it[b] > 0) ? 1.f : 0.f);
}

// ---------------------------------------------------------------------------
// finalize2: vkey/lkey outputs (+0.01*S broadcast) and new_h[0]/new_c[0]
// (= h_att / c_att). kvs written by attn_mega.
// ---------------------------------------------------------------------------
constexpr long VK = (long)B * NV * D;
constexpr long LK = (long)B * NL * D;

__global__ __launch_bounds__(256) void finalize2(
    const float* __restrict__ vkey0, const float* __restrict__ lkey0,
    const float* __restrict__ S, const float* __restrict__ h_att,
    const float* __restrict__ c_att, float* __restrict__ out) {
  long idx = ((long)blockIdx.x * 256 + threadIdx.x) * 4;
  if (idx < VK) {
    int b = (int)(idx / (NV * 1024));
    int d = (int)(idx & 1023);
    ST4(out + O1 + idx, LD4(vkey0 + idx) + LD4(S + (long)b * 1024 + d) * 0.01f);
  } else if (idx < VK + LK) {
    long r = idx - VK;
    int b = (int)(r / (NL * 1024));
    int d = (int)(r & 1023);
    ST4(out + O2 + r, LD4(lkey0 + r) + LD4(S + (long)b * 1024 + d) * 0.01f);
  } else if (idx < VK + LK + BD) {
    long r = idx - VK - LK;
    ST4(out + O4 + r, LD4(h_att + r));    // new_h[0]
  } else if (idx < VK + LK + 2L * BD) {
    long r = idx - VK - LK - BD;
    ST4(out + O5 + r, LD4(c_att + r));    // new_c[0]
  }
}

// ---------------------------------------------------------------------------
extern "C" void kernel_launch(void* const* d_in, const int* in_sizes, int n_in,
                              void* d_out, int out_size, void* d_ws, size_t ws_size,
                              hipStream_t stream) {
  const float* xt   = (const float*)d_in[0];
  const int*   it   = (const int*)d_in[1];
  const float* fc   = (const float*)d_in[2];
  const float* vval = (const float*)d_in[3];
  const float* vkey = (const float*)d_in[4];
  const float* lval = (const float*)d_in[5];
  const float* lkey = (const float*)d_in[6];
  const float* kv0  = (const float*)d_in[7];
  const float* sh   = (const float*)d_in[8];   // [2,B,D]
  const float* sc   = (const float*)d_in[9];   // [2,B,D]
  // d_in[10] = max_att_step (4)
  const float* aWih = (const float*)d_in[11];  // [4096,3072]
  const float* aWhh = (const float*)d_in[12];  // [4096,1024]
  const float* abih = (const float*)d_in[13];
  const float* abhh = (const float*)d_in[14];
  const float* lWih = (const float*)d_in[15];  // [4096,3072]
  const float* lWhh = (const float*)d_in[16];  // [4096,1024]
  const float* lbih = (const float*)d_in[17];
  const float* lbhh = (const float*)d_in[18];
  const float* cW1  = (const float*)d_in[19];  // [1024,1024]
  const float* cb1  = (const float*)d_in[20];
  const float* cW2  = (const float*)d_in[21];  // [1,1024]
  const float* cb2  = (const float*)d_in[22];

  float* ws = (float*)d_ws;
  float* gpA   = ws + OFF_GPA;
  float* gpLB  = ws + OFF_GPLB;
  float* lbase = ws + OFF_LBASE;
  float* gpB   = ws + OFF_GPB;
  float* gpC0  = ws + OFF_GPC0;
  float* gpC1  = ws + OFF_GPC1;
  float* h_att = ws + OFF_HATT2;
  float* c_att = ws + OFF_CATT2;
  float* hB    = ws + OFF_HLB;
  float* cB    = ws + OFF_CLB;
  float* vctxB = ws + OFF_VCTXB;
  float* lctxB = ws + OFF_LCTXB;
  float* Sbuf  = ws + OFF_S2;

  const float* sh1 = sh + BD;  // state_h[1]
  const float* sc0 = sc;       // state_c[0]
  const float* sc1 = sc + BD;  // state_c[1]
  float* out = (float*)d_out;

  // 1) att gates: [sh1,fc,xt]@aWih^T + sh0@aWhh^T, K pairs split in 2
  {
    GemmArgs ga;
    ga.A[0] = sh1;       ga.W[0] = aWih;        ga.wstride[0] = 3072;
    ga.A[1] = sh1 + 512; ga.W[1] = aWih + 512;  ga.wstride[1] = 3072;
    ga.A[2] = fc;        ga.W[2] = aWih + 1024; ga.wstride[2] = 3072;
    ga.A[3] = fc + 512;  ga.W[3] = aWih + 1536; ga.wstride[3] = 3072;
    ga.A[4] = xt;        ga.W[4] = aWih + 2048; ga.wstride[4] = 3072;
    ga.A[5] = xt + 512;  ga.W[5] = aWih + 2560; ga.wstride[5] = 3072;
    ga.A[6] = sh;        ga.W[6] = aWhh;        ga.wstride[6] = 1024;
    ga.A[7] = sh + 512;  ga.W[7] = aWhh + 512;  ga.wstride[7] = 1024;
    ga.klen = 512;
    gemm_mfma<<<dim3(64, 1, 8), 256, 0, stream>>>(ga, 4096, SL, gpA);
  }
  // 2) att LSTM -> h_att, c_att
  lstm_att<<<128, 256, 0, stream>>>(gpA, abih, abhh, sc0, h_att, c_att);

  // 3) lbase partials: sh1@lWhh^T + h_att@lWih[:,2048:]^T (K quarters)
  {
    GemmArgs ga;
#pragma unroll
    for (int q = 0; q < 4; ++q) {
      ga.A[q] = sh1 + q * 256;
      ga.W[q] = lWhh + q * 256;
      ga.wstride[q] = 1024;
      ga.A[4 + q] = h_att + q * 256;
      ga.W[4 + q] = lWih + 2048 + q * 256;
      ga.wstride[4 + q] = 3072;
    }
    ga.klen = 256;
    gemm_mfma<<<dim3(64, 1, 8), 256, 0, stream>>>(ga, 4096, SL, gpLB);
  }
  // 4) lbase reduce (+ both biases)
  reduce8<<<512, 256, 0, stream>>>(gpLB, lbih, lbhh, lbase);

  // 5) all 4 attention steps (kvs recurrence internal); writes out kvs section
  attn_mega<<<128, 1024, 0, stream>>>(h_att, kv0, vkey, lkey, vval, lval,
                                      vctxB, lctxB, out + O6);

  // 6) batched loop gates: M=512; lWih read once per M/128 = 4x.
  {
    GemmArgs ga;
    ga.A[0] = vctxB; ga.W[0] = lWih;        ga.wstride[0] = 3072;
    ga.A[1] = lctxB; ga.W[1] = lWih + 1024; ga.wstride[1] = 3072;
#pragma unroll
    for (int z = 2; z < 8; ++z) { ga.A[z] = vctxB; ga.W[z] = lWih; ga.wstride[z] = 3072; }
    ga.klen = 1024;
    gemm_mfma<<<dim3(64, 4, 2), 256, 0, stream>>>(ga, 4096, SLB, gpB);
  }
  // 7) batched lang LSTM
  lstm_batch<<<512, 256, 0, stream>>>(gpB, lbase, sc1, hB, cB);

  // 8) batched conf GEMM: M=512, N=1024, K=1024 split in 2
  {
    GemmArgs ga;
    ga.A[0] = hB;       ga.W[0] = cW1;       ga.wstride[0] = 1024;
    ga.A[1] = hB + 512; ga.W[1] = cW1 + 512; ga.wstride[1] = 1024;
#pragma unroll
    for (int z = 2; z < 8; ++z) { ga.A[z] = hB; ga.W[z] = cW1; ga.wstride[z] = 1024; }
    ga.klen = 512;
    gemm_mfma<<<dim3(16, 4, 2), 256, 0, stream>>>(ga, 1024, 524288, gpC0);
  }
  // 9) halting scan -> outA, new_h[1], new_c[1], cost, S
  halt_scan<<<128, 256, 0, stream>>>(gpC0, gpC1, cb1, cW2, cb2, hB, cB, it,
                                     Sbuf, out);
  // 10) key outputs + new_h[0]/new_c[0]
  finalize2<<<7424, 256, 0, stream>>>(vkey, lkey, Sbuf, h_att, c_att, out);
}

// Round 8
// 148.021 us; speedup vs baseline: 10.2270x; 1.0186x over previous
//
#include <hip/hip_runtime.h>
#include <hip/hip_bf16.h>

// Sizes (fixed by the reference setup)
constexpr int B  = 128;
constexpr int D  = 1024;
constexpr int NV = 36;
constexpr int NL = 20;
constexpr int BD = B * D;              // 131072
constexpr float EPS = 0.01f;
constexpr int NSLOT = 8;

// Workspace layout (floats)
constexpr long SL  = 524288;                     // [128][4096] slot
constexpr long SLB = 2097152;                    // [512][4096] slot
constexpr long OFF_GPA   = 0;                    // 8 slots (att gate partials)
constexpr long OFF_GPLB  = OFF_GPA + 8 * SL;     // 8 slots (lbase partials)
constexpr long OFF_LBASE = OFF_GPLB + 8 * SL;    // [128][4096] (incl. biases)
constexpr long OFF_GPB   = OFF_LBASE + SL;       // 2 slots [512][4096] (loop gates)
constexpr long OFF_GPC0  = OFF_GPB + 2 * SLB;    // conf slot 0 [512][1024]
constexpr long OFF_GPC1  = OFF_GPC0 + 524288;    // conf slot 1
constexpr long OFF_HATT2 = OFF_GPC1 + 524288;    // h_att [128][1024]
constexpr long OFF_CATT2 = OFF_HATT2 + BD;
constexpr long OFF_HLB   = OFF_CATT2 + BD;       // h_lang batched [512][1024]
constexpr long OFF_CLB   = OFF_HLB + 524288;
constexpr long OFF_VCTXB = OFF_CLB + 524288;     // vctx batched [512][1024]
constexpr long OFF_LCTXB = OFF_VCTXB + 524288;
constexpr long OFF_S2    = OFF_LCTXB + 524288;   // S = sum h_lang [128][1024]
constexpr long OFF_VVB   = OFF_S2 + BD;          // bf16 vval cache (2,359,296 f-slots)
constexpr long OFF_LVB   = OFF_VVB + 2359296;    // bf16 lval cache (1,310,720 f-slots)

typedef float f32x4 __attribute__((ext_vector_type(4)));
typedef short s16x8 __attribute__((ext_vector_type(8)));

__device__ __forceinline__ float sigf(float x) { return 1.f / (1.f + expf(-x)); }

__device__ __forceinline__ short f2bf(float f) {
  __hip_bfloat16 h = __float2bfloat16(f);
  return *reinterpret_cast<short*>(&h);
}
__device__ __forceinline__ float bf2f(short s) {
  unsigned u = ((unsigned)(unsigned short)s) << 16;
  return __uint_as_float(u);
}

__device__ __forceinline__ f32x4 LD4(const float* p) { return *(const f32x4*)p; }
__device__ __forceinline__ void ST4(float* p, f32x4 v) { *(f32x4*)p = v; }

// ---------------------------------------------------------------------------
// MFMA bf16 GEMM, split-K partials, double-buffered LDS, tile BM=128 BN=64
// BK=64. grid (N/64, M/128, KS); block 256 = 4 waves (2x2), wave = 64x32 out.
// partial[z][M][N] = A_z @ W_z^T   (z pointers pre-offset; A stride 1024)
// ---------------------------------------------------------------------------
struct GemmArgs {
  const float* A[NSLOT];
  const float* W[NSLOT];
  long wstride[NSLOT];
  int klen;                // K per z (multiple of 64)
};

__global__ __launch_bounds__(256, 2) void gemm_mfma(GemmArgs ga, int N,
                                                    long pstride,
                                                    float* __restrict__ gpart) {
  const int z = blockIdx.z;
  const float* __restrict__ A = ga.A[z];
  const float* __restrict__ W = ga.W[z];
  const long wstr = ga.wstride[z];
  const int brow = blockIdx.y * 128;
  const int bcol = blockIdx.x * 64;
  float* __restrict__ out = gpart + (long)z * pstride;

  __shared__ __align__(16) short As[2][128][72];
  __shared__ __align__(16) short Bs[2][64][72];

  const int tid = threadIdx.x;
  const int wave = tid >> 6, lane = tid & 63;
  const int wr = wave >> 1, wc = wave & 1;
  const int lrow = lane & 15;
  const int lk8  = (lane >> 4) * 8;
  const int sr = tid >> 4;          // 0..15
  const int sc4 = (tid & 15) * 4;   // 0..60

  f32x4 acc[4][2];
#pragma unroll
  for (int m = 0; m < 4; ++m)
#pragma unroll
    for (int n = 0; n < 2; ++n) acc[m][n] = (f32x4){0.f, 0.f, 0.f, 0.f};

  float4 ra[8], rw[4];
#define LOAD_TILE(KT)                                                          \
  {                                                                            \
    const int kb = (KT) * 64;                                                  \
    _Pragma("unroll") for (int i = 0; i < 8; ++i) {                            \
      const int r = sr + i * 16;                                               \
      ra[i] = *(const float4*)(A + (long)(brow + r) * 1024 + kb + sc4);        \
    }                                                                          \
    _Pragma("unroll") for (int i = 0; i < 4; ++i) {                            \
      const int r = sr + i * 16;                                               \
      rw[i] = *(const float4*)(W + (long)(bcol + r) * wstr + kb + sc4);        \
    }                                                                          \
  }
#define WRITE_TILE(BUF)                                                        \
  {                                                                            \
    _Pragma("unroll") for (int i = 0; i < 8; ++i) {                            \
      const int r = sr + i * 16;                                               \
      *(short4*)(&As[BUF][r][sc4]) =                                           \
          short4{f2bf(ra[i].x), f2bf(ra[i].y), f2bf(ra[i].z), f2bf(ra[i].w)};  \
    }                                                                          \
    _Pragma("unroll") for (int i = 0; i < 4; ++i) {                            \
      const int r = sr + i * 16;                                               \
      *(short4*)(&Bs[BUF][r][sc4]) =                                           \
          short4{f2bf(rw[i].x), f2bf(rw[i].y), f2bf(rw[i].z), f2bf(rw[i].w)};  \
    }                                                                          \
  }

  const int ntiles = ga.klen / 64;
  LOAD_TILE(0);
  WRITE_TILE(0);
  __syncthreads();
  for (int kt = 0; kt < ntiles; ++kt) {
    const int cur = kt & 1;
    const bool more = (kt + 1 < ntiles);
    if (more) LOAD_TILE(kt + 1);  // in flight during MFMA phase
#pragma unroll
    for (int kk = 0; kk < 64; kk += 32) {
      s16x8 af[4], bf[2];
#pragma unroll
      for (int m = 0; m < 4; ++m)
        af[m] = *(const s16x8*)(&As[cur][wr * 64 + m * 16 + lrow][kk + lk8]);
#pragma unroll
      for (int n = 0; n < 2; ++n)
        bf[n] = *(const s16x8*)(&Bs[cur][wc * 32 + n * 16 + lrow][kk + lk8]);
#pragma unroll
      for (int m = 0; m < 4; ++m)
#pragma unroll
        for (int n = 0; n < 2; ++n)
          acc[m][n] = __builtin_amdgcn_mfma_f32_16x16x32_bf16(
              af[m], bf[n], acc[m][n], 0, 0, 0);
    }
    if (more) WRITE_TILE(1 - cur);
    __syncthreads();
  }
#undef LOAD_TILE
#undef WRITE_TILE

  // C/D layout: col=lane&15, row=(lane>>4)*4+reg
#pragma unroll
  for (int m = 0; m < 4; ++m) {
#pragma unroll
    for (int n = 0; n < 2; ++n) {
      const int col = bcol + wc * 32 + n * 16 + lrow;
#pragma unroll
      for (int r = 0; r < 4; ++r) {
        const int row = brow + wr * 64 + m * 16 + (lane >> 4) * 4 + r;
        out[(long)row * N + col] = acc[m][n][r];
      }
    }
  }
}

// ---------------------------------------------------------------------------
// att LSTM cell: gates = sum of 8 partials + bih + bhh -> h_att, c_att
// ---------------------------------------------------------------------------
__global__ __launch_bounds__(256) void lstm_att(
    const float* __restrict__ gp, const float* __restrict__ bih,
    const float* __restrict__ bhh, const float* __restrict__ c_prev,
    float* __restrict__ h, float* __restrict__ c) {
  long idx = ((long)blockIdx.x * 256 + threadIdx.x) * 4;
  if (idx >= BD) return;
  int b = (int)(idx >> 10), d = (int)(idx & 1023);
  const long base = (long)b * 4096 + d;
  f32x4 g[4];
#pragma unroll
  for (int gi = 0; gi < 4; ++gi) {
    const long o = base + gi * 1024;
    f32x4 v = LD4(bih + gi * 1024 + d) + LD4(bhh + gi * 1024 + d);
#pragma unroll
    for (int s = 0; s < NSLOT; ++s) v += LD4(gp + s * SL + o);
    g[gi] = v;
  }
  f32x4 cp = LD4(c_prev + idx), cc, hh;
#pragma unroll
  for (int j = 0; j < 4; ++j) {
    float ccj = sigf(g[1][j]) * cp[j] + sigf(g[0][j]) * tanhf(g[2][j]);
    cc[j] = ccj;
    hh[j] = sigf(g[3][j]) * tanhf(ccj);
  }
  ST4(c + idx, cc);
  ST4(h + idx, hh);
}

// ---------------------------------------------------------------------------
// reduce8: lbase = sum of 8 partials + bih + bhh
// ---------------------------------------------------------------------------
__global__ __launch_bounds__(256) void reduce8(
    const float* __restrict__ gp, const float* __restrict__ bih,
    const float* __restrict__ bhh, float* __restrict__ out) {
  long idx = ((long)blockIdx.x * 256 + threadIdx.x) * 4;
  if (idx >= (long)B * 4096) return;
  int col = (int)(idx & 4095);
  f32x4 v = LD4(bih + col) + LD4(bhh + col);
#pragma unroll
  for (int s = 0; s < NSLOT; ++s) v += LD4(gp + s * SL + idx);
  ST4(out + idx, v);
}

// ---------------------------------------------------------------------------
// attn_mega v2: all 4 attention steps per batch element, 1024 threads.
// Keys staged ONCE into LDS as bf16 (112 KB) -> all logits are LDS-only.
// Values: step 0 reads f32 and writes a bf16 ws cache; steps 1-3 read bf16
// (half bytes, L3-resident). kvs recurrence in registers. Softmax over
// ORIGINAL keys (slot-uniform key update cancels in softmax).
// ---------------------------------------------------------------------------
__global__ __launch_bounds__(1024) void attn_mega(
    const float* __restrict__ h_att, const float* __restrict__ kv0,
    const float* __restrict__ vkey, const float* __restrict__ lkey,
    const float* __restrict__ vval, const float* __restrict__ lval,
    float* __restrict__ vctxB, float* __restrict__ lctxB,
    __hip_bfloat16* __restrict__ vvb, __hip_bfloat16* __restrict__ lvb,
    float* __restrict__ out_kvs) {
  const int b = blockIdx.x, tid = threadIdx.x;   // tid = d column
  __shared__ short K[56][1024];                  // 112 KB bf16 keys
  __shared__ float q[1024];
  __shared__ float wgt[64];
  const int wave = tid >> 6, lane = tid & 63;

  // stage all 56 keys (f32 global, coalesced float4 -> bf16 LDS)
  for (int i = tid; i < 56 * 256; i += 1024) {
    const int r = i >> 8, c4 = (i & 255) * 4;
    const float* kp = (r < NV) ? vkey + ((long)b * NV + r) * 1024
                               : lkey + ((long)b * NL + (r - NV)) * 1024;
    float4 v = *(const float4*)(kp + c4);
    *(short4*)(&K[r][c4]) = short4{f2bf(v.x), f2bf(v.y), f2bf(v.z), f2bf(v.w)};
  }

  const float ha = h_att[(long)b * 1024 + tid];
  float kv = kv0[(long)b * 1024 + tid];

  for (int step = 0; step < 4; ++step) {
    q[tid] = ha + kv;
    __syncthreads();   // orders K staging (iter 0) and q writes before reads
    // logits: 56 keys over 16 waves, pure LDS
    for (int n = wave; n < NV + NL; n += 16) {
      float s = 0.f;
#pragma unroll
      for (int j = 0; j < 2; ++j) {
        const int base = lane * 8 + j * 512;
        s16x8 k8 = *(const s16x8*)(&K[n][base]);
        f32x4 q0 = *(const f32x4*)(&q[base]);
        f32x4 q1 = *(const f32x4*)(&q[base + 4]);
#pragma unroll
        for (int e = 0; e < 4; ++e) {
          s += bf2f(k8[e]) * q0[e];
          s += bf2f(k8[e + 4]) * q1[e];
        }
      }
      for (int m = 32; m >= 1; m >>= 1) s += __shfl_xor(s, m);
      if (lane == 0) wgt[n] = s * (1.0f / 32.0f);
    }
    __syncthreads();
    // softmax (wave0: visual, wave1: language)
    if (wave == 0) {
      float x = (lane < NV) ? wgt[lane] : -1e30f;
      float m = x;
      for (int k = 32; k >= 1; k >>= 1) m = fmaxf(m, __shfl_xor(m, k));
      float e = (lane < NV) ? expf(x - m) : 0.f;
      float ssum = e;
      for (int k = 32; k >= 1; k >>= 1) ssum += __shfl_xor(ssum, k);
      if (lane < NV) wgt[lane] = e / ssum;
    } else if (wave == 1) {
      float x = (lane < NL) ? wgt[NV + lane] : -1e30f;
      float m = x;
      for (int k = 32; k >= 1; k >>= 1) m = fmaxf(m, __shfl_xor(m, k));
      float e = (lane < NL) ? expf(x - m) : 0.f;
      float ssum = e;
      for (int k = 32; k >= 1; k >>= 1) ssum += __shfl_xor(ssum, k);
      if (lane < NL) wgt[NV + lane] = e / ssum;
    }
    __syncthreads();
    // context + kvs update (1 col/thread, coalesced)
    float vc = 0.f, lc = 0.f;
    if (step == 0) {
      const float* vp = vval + (long)b * NV * 1024 + tid;
      __hip_bfloat16* vb = vvb + (long)b * NV * 1024 + tid;
#pragma unroll 6
      for (int n = 0; n < NV; ++n) {
        float v = vp[(long)n * 1024];
        vc += v * wgt[n];
        vb[(long)n * 1024] = __float2bfloat16(v);
      }
      const float* lp = lval + (long)b * NL * 1024 + tid;
      __hip_bfloat16* lb = lvb + (long)b * NL * 1024 + tid;
#pragma unroll 5
      for (int n = 0; n < NL; ++n) {
        float v = lp[(long)n * 1024];
        lc += v * wgt[NV + n];
        lb[(long)n * 1024] = __float2bfloat16(v);
      }
    } else {
      const __hip_bfloat16* vb = vvb + (long)b * NV * 1024 + tid;
#pragma unroll 6
      for (int n = 0; n < NV; ++n)
        vc += __bfloat162float(vb[(long)n * 1024]) * wgt[n];
      const __hip_bfloat16* lb = lvb + (long)b * NL * 1024 + tid;
#pragma unroll 5
      for (int n = 0; n < NL; ++n)
        lc += __bfloat162float(lb[(long)n * 1024]) * wgt[NV + n];
    }
    const long orow = ((long)step * 128 + b) * 1024 + tid;
    vctxB[orow] = vc;
    lctxB[orow] = lc;
    kv = tanhf(kv + vc + lc);
    __syncthreads();  // protect q/wgt for next step
  }
  out_kvs[(long)b * 1024 + tid] = kv;
}

// ---------------------------------------------------------------------------
// batched lang LSTM (M=512 = 4 steps x 128): gates = gpB0+gpB1 + lbase[b]
// (lbase includes both biases); c_prev = sc1[b] (state constant across steps).
// ---------------------------------------------------------------------------
__global__ __launch_bounds__(256) void lstm_batch(
    const float* __restrict__ gpB, const float* __restrict__ lbase,
    const float* __restrict__ sc1, float* __restrict__ hB,
    float* __restrict__ cB) {
  long idx = ((long)blockIdx.x * 256 + threadIdx.x) * 4;
  if (idx >= 512L * 1024) return;
  const int row = (int)(idx >> 10);   // step*128+b
  const int b = row & 127;
  const int d = (int)(idx & 1023);
  const long base = (long)row * 4096 + d;
  const long lbbase = (long)b * 4096 + d;
  f32x4 g[4];
#pragma unroll
  for (int gi = 0; gi < 4; ++gi) {
    const long o = gi * 1024;
    g[gi] = LD4(gpB + base + o) + LD4(gpB + SLB + base + o) +
            LD4(lbase + lbbase + o);
  }
  f32x4 cp = LD4(sc1 + (long)b * 1024 + d), cc, hh;
#pragma unroll
  for (int j = 0; j < 4; ++j) {
    float ccj = sigf(g[1][j]) * cp[j] + sigf(g[0][j]) * tanhf(g[2][j]);
    cc[j] = ccj;
    hh[j] = sigf(g[3][j]) * tanhf(ccj);
  }
  ST4(cB + idx, cc);
  ST4(hB + idx, hh);
}

// ---------------------------------------------------------------------------
// halt_scan: per-b halting recurrence over 4 steps; writes outA / new_h[1] /
// new_c[1] / cost into d_out and S = sum h_lang.
// ---------------------------------------------------------------------------
constexpr long O1 = BD;
constexpr long O2 = O1 + (long)B * NV * D;
constexpr long O3 = O2 + (long)B * NL * D;
constexpr long O4 = O3 + B;
constexpr long O5 = O4 + 2L * BD;
constexpr long O6 = O5 + 2L * BD;
constexpr long O7 = O6 + BD;

__global__ __launch_bounds__(256) void halt_scan(
    const float* __restrict__ gpc0, const float* __restrict__ gpc1,
    const float* __restrict__ cb1, const float* __restrict__ W2,
    const float* __restrict__ b2, const float* __restrict__ hB,
    const float* __restrict__ cB, const int* __restrict__ it,
    float* __restrict__ Sout, float* __restrict__ out) {
  const int b = blockIdx.x, tid = threadIdx.x;
  const int d0 = tid * 4;
  __shared__ float red[256];
  __shared__ float p_sh;
  const f32x4 w4 = LD4(W2 + d0);
  const f32x4 cb = LD4(cb1 + d0);
  f32x4 hl_acc = (f32x4){0.f, 0.f, 0.f, 0.f}, cl_acc = hl_acc, s_acc = hl_acc;
  float a = 0.f, sel = 1.f, cost = 0.f;

  for (int i = 0; i < 4; ++i) {
    const long o = ((long)i * 128 + b) * 1024 + d0;
    f32x4 rv = LD4(gpc0 + o) + LD4(gpc1 + o) + cb;
    float part = 0.f;
#pragma unroll
    for (int j = 0; j < 4; ++j) part += fmaxf(rv[j], 0.f) * w4[j];
    red[tid] = part;
    __syncthreads();
    for (int s = 128; s > 0; s >>= 1) {
      if (tid < s) red[tid] += red[tid + s];
      __syncthreads();
    }
    if (tid == 0) p_sh = sigf(red[0] + b2[0]);
    __syncthreads();
    const float p = p_sh;
    const float bs = p * (1.f - a) * sel;
    f32x4 hl = LD4(hB + o), cl = LD4(cB + o);
    hl_acc += hl * bs;
    cl_acc += cl * bs;
    s_acc += hl;                        // key update unmasked in reference
    cost += (float)(i + 1) * (1.f - p) * sel;
    a += bs;
    sel = (a < 1.f - EPS) ? sel : 0.f;
    __syncthreads();                    // p_sh reuse
  }
  const float inv_a = 1.f / a;
  const long ob = (long)b * 1024 + d0;
  ST4(out + ob, hl_acc * inv_a);             // outA
  ST4(out + O4 + BD + ob, hl_acc * inv_a);   // new_h[1]
  ST4(out + O5 + BD + ob, cl_acc * inv_a);   // new_c[1]
  ST4(Sout + ob, s_acc);
  if (tid == 0) out[O3 + b] = cost * ((it[b] > 0) ? 1.f : 0.f);
}

// ---------------------------------------------------------------------------
// finalize2: vkey/lkey outputs (+0.01*S broadcast) and new_h[0]/new_c[0]
// (= h_att / c_att). kvs written by attn_mega.
// ---------------------------------------------------------------------------
constexpr long VK = (long)B * NV * D;
constexpr long LK = (long)B * NL * D;

__global__ __launch_bounds__(256) void finalize2(
    const float* __restrict__ vkey0, const float* __restrict__ lkey0,
    const float* __restrict__ S, const float* __restrict__ h_att,
    const float* __restrict__ c_att, float* __restrict__ out) {
  long idx = ((long)blockIdx.x * 256 + threadIdx.x) * 4;
  if (idx < VK) {
    int b = (int)(idx / (NV * 1024));
    int d = (int)(idx & 1023);
    ST4(out + O1 + idx, LD4(vkey0 + idx) + LD4(S + (long)b * 1024 + d) * 0.01f);
  } else if (idx < VK + LK) {
    long r = idx - VK;
    int b = (int)(r / (NL * 1024));
    int d = (int)(r & 1023);
    ST4(out + O2 + r, LD4(lkey0 + r) + LD4(S + (long)b * 1024 + d) * 0.01f);
  } else if (idx < VK + LK + BD) {
    long r = idx - VK - LK;
    ST4(out + O4 + r, LD4(h_att + r));    // new_h[0]
  } else if (idx < VK + LK + 2L * BD) {
    long r = idx - VK - LK - BD;
    ST4(out + O5 + r, LD4(c_att + r));    // new_c[0]
  }
}

// ---------------------------------------------------------------------------
extern "C" void kernel_launch(void* const* d_in, const int* in_sizes, int n_in,
                              void* d_out, int out_size, void* d_ws, size_t ws_size,
                              hipStream_t stream) {
  const float* xt   = (const float*)d_in[0];
  const int*   it   = (const int*)d_in[1];
  const float* fc   = (const float*)d_in[2];
  const float* vval = (const float*)d_in[3];
  const float* vkey = (const float*)d_in[4];
  const float* lval = (const float*)d_in[5];
  const float* lkey = (const float*)d_in[6];
  const float* kv0  = (const float*)d_in[7];
  const float* sh   = (const float*)d_in[8];   // [2,B,D]
  const float* sc   = (const float*)d_in[9];   // [2,B,D]
  // d_in[10] = max_att_step (4)
  const float* aWih = (const float*)d_in[11];  // [4096,3072]
  const float* aWhh = (const float*)d_in[12];  // [4096,1024]
  const float* abih = (const float*)d_in[13];
  const float* abhh = (const float*)d_in[14];
  const float* lWih = (const float*)d_in[15];  // [4096,3072]
  const float* lWhh = (const float*)d_in[16];  // [4096,1024]
  const float* lbih = (const float*)d_in[17];
  const float* lbhh = (const float*)d_in[18];
  const float* cW1  = (const float*)d_in[19];  // [1024,1024]
  const float* cb1  = (const float*)d_in[20];
  const float* cW2  = (const float*)d_in[21];  // [1,1024]
  const float* cb2  = (const float*)d_in[22];

  float* ws = (float*)d_ws;
  float* gpA   = ws + OFF_GPA;
  float* gpLB  = ws + OFF_GPLB;
  float* lbase = ws + OFF_LBASE;
  float* gpB   = ws + OFF_GPB;
  float* gpC0  = ws + OFF_GPC0;
  float* gpC1  = ws + OFF_GPC1;
  float* h_att = ws + OFF_HATT2;
  float* c_att = ws + OFF_CATT2;
  float* hB    = ws + OFF_HLB;
  float* cB    = ws + OFF_CLB;
  float* vctxB = ws + OFF_VCTXB;
  float* lctxB = ws + OFF_LCTXB;
  float* Sbuf  = ws + OFF_S2;
  __hip_bfloat16* vvb = (__hip_bfloat16*)(ws + OFF_VVB);
  __hip_bfloat16* lvb = (__hip_bfloat16*)(ws + OFF_LVB);

  const float* sh1 = sh + BD;  // state_h[1]
  const float* sc0 = sc;       // state_c[0]
  const float* sc1 = sc + BD;  // state_c[1]
  float* out = (float*)d_out;

  // 1) att gates: [sh1,fc,xt]@aWih^T + sh0@aWhh^T, K pairs split in 2
  {
    GemmArgs ga;
    ga.A[0] = sh1;       ga.W[0] = aWih;        ga.wstride[0] = 3072;
    ga.A[1] = sh1 + 512; ga.W[1] = aWih + 512;  ga.wstride[1] = 3072;
    ga.A[2] = fc;        ga.W[2] = aWih + 1024; ga.wstride[2] = 3072;
    ga.A[3] = fc + 512;  ga.W[3] = aWih + 1536; ga.wstride[3] = 3072;
    ga.A[4] = xt;        ga.W[4] = aWih + 2048; ga.wstride[4] = 3072;
    ga.A[5] = xt + 512;  ga.W[5] = aWih + 2560; ga.wstride[5] = 3072;
    ga.A[6] = sh;        ga.W[6] = aWhh;        ga.wstride[6] = 1024;
    ga.A[7] = sh + 512;  ga.W[7] = aWhh + 512;  ga.wstride[7] = 1024;
    ga.klen = 512;
    gemm_mfma<<<dim3(64, 1, 8), 256, 0, stream>>>(ga, 4096, SL, gpA);
  }
  // 2) att LSTM -> h_att, c_att
  lstm_att<<<128, 256, 0, stream>>>(gpA, abih, abhh, sc0, h_att, c_att);

  // 3) lbase partials: sh1@lWhh^T + h_att@lWih[:,2048:]^T (K quarters)
  {
    GemmArgs ga;
#pragma unroll
    for (int q = 0; q < 4; ++q) {
      ga.A[q] = sh1 + q * 256;
      ga.W[q] = lWhh + q * 256;
      ga.wstride[q] = 1024;
      ga.A[4 + q] = h_att + q * 256;
      ga.W[4 + q] = lWih + 2048 + q * 256;
      ga.wstride[4 + q] = 3072;
    }
    ga.klen = 256;
    gemm_mfma<<<dim3(64, 1, 8), 256, 0, stream>>>(ga, 4096, SL, gpLB);
  }
  // 4) lbase reduce (+ both biases)
  reduce8<<<512, 256, 0, stream>>>(gpLB, lbih, lbhh, lbase);

  // 5) all 4 attention steps (keys LDS-resident, values bf16-cached)
  attn_mega<<<128, 1024, 0, stream>>>(h_att, kv0, vkey, lkey, vval, lval,
                                      vctxB, lctxB, vvb, lvb, out + O6);

  // 6) batched loop gates: M=512; lWih read 4x via L3.
  {
    GemmArgs ga;
    ga.A[0] = vctxB; ga.W[0] = lWih;        ga.wstride[0] = 3072;
    ga.A[1] = lctxB; ga.W[1] = lWih + 1024; ga.wstride[1] = 3072;
#pragma unroll
    for (int z = 2; z < 8; ++z) { ga.A[z] = vctxB; ga.W[z] = lWih; ga.wstride[z] = 3072; }
    ga.klen = 1024;
    gemm_mfma<<<dim3(64, 4, 2), 256, 0, stream>>>(ga, 4096, SLB, gpB);
  }
  // 7) batched lang LSTM
  lstm_batch<<<512, 256, 0, stream>>>(gpB, lbase, sc1, hB, cB);

  // 8) batched conf GEMM: M=512, N=1024, K=1024 split in 2
  {
    GemmArgs ga;
    ga.A[0] = hB;       ga.W[0] = cW1;       ga.wstride[0] = 1024;
    ga.A[1] = hB + 512; ga.W[1] = cW1 + 512; ga.wstride[1] = 1024;
#pragma unroll
    for (int z = 2; z < 8; ++z) { ga.A[z] = hB; ga.W[z] = cW1; ga.wstride[z] = 1024; }
    ga.klen = 512;
    gemm_mfma<<<dim3(16, 4, 2), 256, 0, stream>>>(ga, 1024, 524288, gpC0);
  }
  // 9) halting scan -> outA, new_h[1], new_c[1], cost, S
  halt_scan<<<128, 256, 0, stream>>>(gpC0, gpC1, cb1, cW2, cb2, hB, cB, it,
                                     Sbuf, out);
  // 10) key outputs + new_h[0]/new_c[0]
  finalize2<<<7424, 256, 0, stream>>>(vkey, lkey, Sbuf, h_att, c_att, out);
}